// Round 1
// baseline (6272.891 us; speedup 1.0000x reference)
//
#include <hip/hip_runtime.h>
#include <math.h>

#define SEQ   2048
#define HID   1024
#define NH    16
#define HD    64
#define NKH   204          // heavy hitters = int(2048*0.1)
#define LCOMP 512          // compressed length = 2048/4
#define NCAT  716          // 204 + 512
#define SCALE 0.125f       // 1/sqrt(64)

// ---------------------------------------------------------------------------
// Tiled f32 GEMM: C[M,N] = A[M,K] @ B[K,N].  64x64 tile, 256 thr, 4x4 micro.
// ---------------------------------------------------------------------------
__global__ __launch_bounds__(256) void gemm_f32(const float* __restrict__ A,
                                                const float* __restrict__ B,
                                                float* __restrict__ C,
                                                int M, int N, int K) {
    __shared__ float As[16][68];   // [k][m], pad 68 -> 16B-aligned float4 rows
    __shared__ float Bs[16][68];   // [k][n]
    int t  = threadIdx.x;
    int tn = t & 15, tm = t >> 4;
    int m0 = blockIdx.y * 64, n0 = blockIdx.x * 64;
    int arow = t >> 2, akq = t & 3;     // A-load map: row 0..63, k-quad 0..3
    int bkr  = t >> 4, bn4 = t & 15;    // B-load map: k-row 0..15, n-quad 0..15
    float acc[4][4] = {};
    for (int kt = 0; kt < K; kt += 16) {
        __syncthreads();
        float4 av = *(const float4*)(A + (size_t)(m0 + arow) * K + kt + akq * 4);
        As[akq*4+0][arow] = av.x;
        As[akq*4+1][arow] = av.y;
        As[akq*4+2][arow] = av.z;
        As[akq*4+3][arow] = av.w;
        *(float4*)&Bs[bkr][bn4*4] =
            *(const float4*)(B + (size_t)(kt + bkr) * N + n0 + bn4 * 4);
        __syncthreads();
        #pragma unroll
        for (int kk = 0; kk < 16; ++kk) {
            float4 a = *(const float4*)&As[kk][tm*4];
            float4 b = *(const float4*)&Bs[kk][tn*4];
            acc[0][0] += a.x*b.x; acc[0][1] += a.x*b.y; acc[0][2] += a.x*b.z; acc[0][3] += a.x*b.w;
            acc[1][0] += a.y*b.x; acc[1][1] += a.y*b.y; acc[1][2] += a.y*b.z; acc[1][3] += a.y*b.w;
            acc[2][0] += a.z*b.x; acc[2][1] += a.z*b.y; acc[2][2] += a.z*b.z; acc[2][3] += a.z*b.w;
            acc[3][0] += a.w*b.x; acc[3][1] += a.w*b.y; acc[3][2] += a.w*b.z; acc[3][3] += a.w*b.w;
        }
    }
    #pragma unroll
    for (int i = 0; i < 4; ++i) {
        float4 o = make_float4(acc[i][0], acc[i][1], acc[i][2], acc[i][3]);
        *(float4*)(C + (size_t)(m0 + tm*4 + i) * N + n0 + tn*4) = o;
    }
}

// ---------------------------------------------------------------------------
// Score stats: per (head, 4 query rows) compute full 2048-key softmax stats:
// entropy, max_attn (=1/l), and accumulate column influence via atomics.
// Scores kept in LDS only (never materialized in HBM).
// ---------------------------------------------------------------------------
__global__ __launch_bounds__(256) void score_stats(const float* __restrict__ q,
                                                   const float* __restrict__ k,
                                                   float* __restrict__ ent,
                                                   float* __restrict__ mxa,
                                                   float* __restrict__ infl) {
    __shared__ float  sc[4][SEQ];      // 32 KB
    __shared__ float  ks[64][68];      // 17.4 KB  (pad 68 for float4 align)
    __shared__ float4 qs[4][16];       // 1 KB
    __shared__ float  mrow[4], lrow[4];
    int h  = blockIdx.x;
    int q0 = blockIdx.y * 4;
    int t  = threadIdx.x;
    {   // load 4 q rows
        int r = t >> 6, d = t & 63;
        ((float*)&qs[r][0])[d] = q[(size_t)(q0 + r) * HID + h * HD + d];
    }
    int j = t & 63, r = t >> 6;
    for (int c = 0; c < SEQ / 64; ++c) {
        __syncthreads();
        #pragma unroll
        for (int wj = 0; wj < 4; ++wj) {          // stage 64 keys x 64 dims
            int idx = wj * 256 + t;               // float4 index 0..1023
            int key = idx >> 4, d4 = idx & 15;
            *(float4*)&ks[key][d4*4] =
                *(const float4*)(k + (size_t)(c*64 + key) * HID + h * HD + d4*4);
        }
        __syncthreads();
        float s = 0.f;
        #pragma unroll
        for (int d4 = 0; d4 < 16; ++d4) {
            float4 a = qs[r][d4];
            float4 b = *(const float4*)&ks[j][d4*4];
            s += a.x*b.x + a.y*b.y + a.z*b.z + a.w*b.w;
        }
        sc[r][c*64 + j] = s * SCALE;
    }
    __syncthreads();
    // phase B: wave w handles row w
    int w = t >> 6, lane = t & 63;
    float m = -1e30f;
    for (int i = 0; i < SEQ/64; ++i) m = fmaxf(m, sc[w][lane + 64*i]);
    #pragma unroll
    for (int off = 32; off; off >>= 1) m = fmaxf(m, __shfl_xor(m, off));
    float l = 0.f;
    for (int i = 0; i < SEQ/64; ++i) l += expf(sc[w][lane + 64*i] - m);
    #pragma unroll
    for (int off = 32; off; off >>= 1) l += __shfl_xor(l, off);
    float e = 0.f;
    for (int i = 0; i < SEQ/64; ++i) {
        float p = expf(sc[w][lane + 64*i] - m) / l;
        e -= p * logf(fmaxf(p, 1e-8f));
    }
    #pragma unroll
    for (int off = 32; off; off >>= 1) e += __shfl_xor(e, off);
    if (lane == 0) {
        ent[h*SEQ + q0 + w] = e;
        mxa[h*SEQ + q0 + w] = 1.f / l;   // max prob = exp(m-m)/l
        mrow[w] = m; lrow[w] = l;
    }
    __syncthreads();
    // phase C: column influence (sum over this block's 4 rows)
    float m0v = mrow[0], m1v = mrow[1], m2v = mrow[2], m3v = mrow[3];
    float l0v = lrow[0], l1v = lrow[1], l2v = lrow[2], l3v = lrow[3];
    for (int i = 0; i < SEQ/256; ++i) {
        int jj = t + 256*i;
        float a = expf(sc[0][jj]-m0v)/l0v + expf(sc[1][jj]-m1v)/l1v
                + expf(sc[2][jj]-m2v)/l2v + expf(sc[3][jj]-m3v)/l3v;
        atomicAdd(&infl[jj], a);
    }
}

__global__ __launch_bounds__(256) void importance_k(const float* __restrict__ ent,
                                                    const float* __restrict__ mxa,
                                                    const float* __restrict__ infl,
                                                    float* __restrict__ imp) {
    int s = blockIdx.x * 256 + threadIdx.x;
    float es = 0.f, ms = 0.f;
    #pragma unroll
    for (int h = 0; h < NH; ++h) { es += ent[h*SEQ + s]; ms += mxa[h*SEQ + s]; }
    imp[s] = (-0.4f*es + 0.3f*ms + 0.3f*infl[s]) * (1.f/16.f);
}

// Deterministic top-k by rank counting (matches lax.top_k set semantics;
// attention is permutation-invariant over the selected set).
__global__ __launch_bounds__(256) void topk_k(const float* __restrict__ imp,
                                              int* __restrict__ hh) {
    __shared__ float si[SEQ];
    int t = threadIdx.x, s = blockIdx.x * 256 + t;
    for (int i = t; i < SEQ; i += 256) si[i] = imp[i];
    __syncthreads();
    float v = si[s];
    int rank = 0;
    for (int i = 0; i < SEQ; ++i) {
        float u = si[i];
        rank += (u > v) || (u == v && i < s);
    }
    if (rank < NKH) hh[rank] = s;
}

// per-(h,s) L2 norm of a 64-dim head vector (one wave each)
__global__ __launch_bounds__(256) void norms_k(const float* __restrict__ x,
                                               float* __restrict__ n) {
    int t = threadIdx.x;
    int wid = blockIdx.x * 4 + (t >> 6);    // 0..32767
    int lane = t & 63;
    int h = wid >> 11, s = wid & 2047;
    float v = x[(size_t)s * HID + h * HD + lane];
    float ss = v * v;
    #pragma unroll
    for (int off = 32; off; off >>= 1) ss += __shfl_xor(ss, off);
    if (lane == 0) n[h*SEQ + s] = sqrtf(ss);
}

// in-place softmax over SEQ per head (one block per head)
__global__ __launch_bounds__(256) void softw_k(float* __restrict__ n) {
    __shared__ float red[8];
    int h = blockIdx.x, t = threadIdx.x, lane = t & 63, w = t >> 6;
    float* nh = n + (size_t)h * SEQ;
    float m = -1e30f;
    for (int i = t; i < SEQ; i += 256) m = fmaxf(m, nh[i]);
    #pragma unroll
    for (int off = 32; off; off >>= 1) m = fmaxf(m, __shfl_xor(m, off));
    if (lane == 0) red[w] = m;
    __syncthreads();
    m = fmaxf(fmaxf(red[0], red[1]), fmaxf(red[2], red[3]));
    float z = 0.f;
    for (int i = t; i < SEQ; i += 256) z += expf(nh[i] - m);
    #pragma unroll
    for (int off = 32; off; off >>= 1) z += __shfl_xor(z, off);
    if (lane == 0) red[4 + w] = z;
    __syncthreads();
    z = red[4] + red[5] + red[6] + red[7];
    for (int i = t; i < SEQ; i += 256) nh[i] = expf(nh[i] - m) / z;
}

// group-4 weighted pooling -> compressed keys/values at cat[h][204+l][:]
__global__ __launch_bounds__(256) void pool_k(const float* __restrict__ src,
                                              const float* __restrict__ w,
                                              float* __restrict__ cat) {
    int g = blockIdx.x * 256 + threadIdx.x;   // 16*512*64
    int d = g & 63, rest = g >> 6;
    int l = rest & 511, h = rest >> 9;
    const float* wp = w + (size_t)h * SEQ + l * 4;
    float w0 = wp[0], w1 = wp[1], w2 = wp[2], w3 = wp[3];
    float wsum = w0 + w1 + w2 + w3 + 1e-8f;
    size_t base = (size_t)(l*4) * HID + h * HD + d;
    float val = src[base]*w0 + src[base+HID]*w1 + src[base+2*HID]*w2 + src[base+3*HID]*w3;
    cat[((size_t)h * NCAT + NKH + l) * HD + d] = val / wsum;
}

// gather heavy-hitter k/v rows into cat[h][0..203][:]
__global__ __launch_bounds__(256) void gather_k(const float* __restrict__ k,
                                                const float* __restrict__ v,
                                                const int* __restrict__ hh,
                                                float* __restrict__ kcat,
                                                float* __restrict__ vcat) {
    int g = blockIdx.x * 256 + threadIdx.x;   // 16*204*64 = 208896 exactly
    int d = g & 63, rest = g >> 6;
    int i = rest % NKH, h = rest / NKH;
    int s = hh[i];
    size_t src = (size_t)s * HID + h * HD + d;
    size_t dst = ((size_t)h * NCAT + i) * HD + d;
    kcat[dst] = k[src];
    vcat[dst] = v[src];
}

// ---------------------------------------------------------------------------
// Final attention: block = (head, 8 queries), 716 keys, LDS-staged K/V chunks.
// ---------------------------------------------------------------------------
__global__ __launch_bounds__(256) void attn_k(const float* __restrict__ q,
                                              const float* __restrict__ kcat,
                                              const float* __restrict__ vcat,
                                              float* __restrict__ ao) {
    __shared__ float  sc[8][720];     // 23 KB scores/probs
    __shared__ float  tile[64][68];   // 17.4 KB staged K or V chunk
    __shared__ float4 qs[8][16];      // 2 KB
    int h = blockIdx.x, q0 = blockIdx.y * 8;
    int t = threadIdx.x;
    for (int i = t; i < 8*64; i += 256) {
        int r = i >> 6, d = i & 63;
        ((float*)&qs[r][0])[d] = q[(size_t)(q0 + r) * HID + h * HD + d];
    }
    const float* kh = kcat + (size_t)h * NCAT * HD;
    const float* vh = vcat + (size_t)h * NCAT * HD;
    int j = t & 63, r0 = t >> 6;
    for (int c = 0; c < 12; ++c) {                 // ceil(716/64)
        int nk = min(64, NCAT - c*64);
        __syncthreads();
        #pragma unroll
        for (int wj = 0; wj < 4; ++wj) {
            int idx = wj * 256 + t;
            int key = idx >> 4, d4 = idx & 15;
            if (key < nk)
                *(float4*)&tile[key][d4*4] =
                    *(const float4*)(kh + (size_t)(c*64 + key) * HD + d4*4);
        }
        __syncthreads();
        if (j < nk) {
            #pragma unroll
            for (int rr = 0; rr < 2; ++rr) {
                int r = r0 + rr*4;
                float s = 0.f;
                #pragma unroll
                for (int d4 = 0; d4 < 16; ++d4) {
                    float4 a = qs[r][d4];
                    float4 b = *(const float4*)&tile[j][d4*4];
                    s += a.x*b.x + a.y*b.y + a.z*b.z + a.w*b.w;
                }
                sc[r][c*64 + j] = s * SCALE;
            }
        }
    }
    __syncthreads();
    // softmax: wave w does rows 2w, 2w+1
    int lane = t & 63, w = t >> 6;
    #pragma unroll
    for (int rr = 0; rr < 2; ++rr) {
        int r = w*2 + rr;
        float m = -1e30f;
        for (int i = lane; i < NCAT; i += 64) m = fmaxf(m, sc[r][i]);
        #pragma unroll
        for (int off = 32; off; off >>= 1) m = fmaxf(m, __shfl_xor(m, off));
        float l = 0.f;
        for (int i = lane; i < NCAT; i += 64) l += expf(sc[r][i] - m);
        #pragma unroll
        for (int off = 32; off; off >>= 1) l += __shfl_xor(l, off);
        float inv = 1.f / l;
        for (int i = lane; i < NCAT; i += 64) sc[r][i] = expf(sc[r][i] - m) * inv;
    }
    // PV: thread -> (row r, float2 d-pair)
    int d2 = t & 31, r = t >> 5;
    float2 acc = make_float2(0.f, 0.f);
    for (int c = 0; c < 12; ++c) {
        int nk = min(64, NCAT - c*64);
        __syncthreads();
        #pragma unroll
        for (int wj = 0; wj < 4; ++wj) {
            int idx = wj * 256 + t;
            int key = idx >> 4, d4 = idx & 15;
            if (key < nk)
                *(float4*)&tile[key][d4*4] =
                    *(const float4*)(vh + (size_t)(c*64 + key) * HD + d4*4);
        }
        __syncthreads();
        for (int jj = 0; jj < nk; ++jj) {
            float pj = sc[r][c*64 + jj];
            float2 vv = *(const float2*)&tile[jj][d2*2];
            acc.x += pj * vv.x;
            acc.y += pj * vv.y;
        }
    }
    *(float2*)(ao + (size_t)(q0 + r) * HID + h * HD + d2*2) = acc;
}

// ---------------------------------------------------------------------------
extern "C" void kernel_launch(void* const* d_in, const int* in_sizes, int n_in,
                              void* d_out, int out_size, void* d_ws, size_t ws_size,
                              hipStream_t stream) {
    const float* x  = (const float*)d_in[0];
    const float* Wq = (const float*)d_in[1];
    const float* Wk = (const float*)d_in[2];
    const float* Wv = (const float*)d_in[3];
    const float* Wo = (const float*)d_in[4];
    float* out = (float*)d_out;

    float* ws   = (float*)d_ws;                 // ~40 MB total
    float* q    = ws;                           // 2048*1024
    float* k    = q    + (size_t)SEQ*HID;
    float* v    = k    + (size_t)SEQ*HID;
    float* ao   = v    + (size_t)SEQ*HID;
    float* ent  = ao   + (size_t)SEQ*HID;       // 16*2048
    float* mxa  = ent  + NH*SEQ;
    float* infl = mxa  + NH*SEQ;                // 2048
    float* imp  = infl + SEQ;                   // 2048
    int*   hh   = (int*)(imp + SEQ);            // 256 slots (204 used)
    float* wk   = (float*)(hh + 256);           // 16*2048
    float* wv   = wk   + NH*SEQ;
    float* kcat = wv   + NH*SEQ;                // 16*716*64
    float* vcat = kcat + (size_t)NH*NCAT*HD;

    dim3 gB(16, 32);   // N/64, M/64 for 2048x1024x1024
    gemm_f32<<<gB, 256, 0, stream>>>(x, Wq, q, SEQ, HID, HID);
    gemm_f32<<<gB, 256, 0, stream>>>(x, Wk, k, SEQ, HID, HID);
    gemm_f32<<<gB, 256, 0, stream>>>(x, Wv, v, SEQ, HID, HID);

    hipMemsetAsync(infl, 0, SEQ * sizeof(float), stream);
    score_stats<<<dim3(NH, SEQ/4), 256, 0, stream>>>(q, k, ent, mxa, infl);
    importance_k<<<SEQ/256, 256, 0, stream>>>(ent, mxa, infl, imp);
    topk_k<<<SEQ/256, 256, 0, stream>>>(imp, hh);

    norms_k<<<NH*SEQ/4, 256, 0, stream>>>(k, wk);
    norms_k<<<NH*SEQ/4, 256, 0, stream>>>(v, wv);
    softw_k<<<NH, 256, 0, stream>>>(wk);
    softw_k<<<NH, 256, 0, stream>>>(wv);
    pool_k<<<NH*LCOMP*HD/256, 256, 0, stream>>>(k, wk, kcat);
    pool_k<<<NH*LCOMP*HD/256, 256, 0, stream>>>(v, wv, vcat);
    gather_k<<<NH*NKH*HD/256, 256, 0, stream>>>(k, v, hh, kcat, vcat);

    attn_k<<<dim3(NH, SEQ/8), 256, 0, stream>>>(q, kcat, vcat, ao);
    gemm_f32<<<gB, 256, 0, stream>>>(ao, Wo, out, SEQ, HID, HID);
}

// Round 2
// 1311.751 us; speedup vs baseline: 4.7821x; 4.7821x over previous
//
#include <hip/hip_runtime.h>
#include <math.h>

#define SEQ   2048
#define HID   1024
#define NH    16
#define HD    64
#define NKH   204          // heavy hitters = int(2048*0.1)
#define LCOMP 512          // compressed length = 2048/4
#define NCAT  716          // 204 + 512
#define NCATP 768          // padded to multiple of 64 (52 pad keys)
#define SCALE 0.125f       // 1/sqrt(64)

// ---------------------------------------------------------------------------
// Tiled f32 GEMM: C[M,N] = A[M,K] @ B[K,N].  64x64 tile, 256 thr, 4x4 micro.
// ---------------------------------------------------------------------------
__global__ __launch_bounds__(256) void gemm_f32(const float* __restrict__ A,
                                                const float* __restrict__ B,
                                                float* __restrict__ C,
                                                int M, int N, int K) {
    __shared__ float As[16][68];   // [k][m], pad 68 -> 16B-aligned float4 rows
    __shared__ float Bs[16][68];   // [k][n]
    int t  = threadIdx.x;
    int tn = t & 15, tm = t >> 4;
    int m0 = blockIdx.y * 64, n0 = blockIdx.x * 64;
    int arow = t >> 2, akq = t & 3;     // A-load map: row 0..63, k-quad 0..3
    int bkr  = t >> 4, bn4 = t & 15;    // B-load map: k-row 0..15, n-quad 0..15
    float acc[4][4] = {};
    for (int kt = 0; kt < K; kt += 16) {
        __syncthreads();
        float4 av = *(const float4*)(A + (size_t)(m0 + arow) * K + kt + akq * 4);
        As[akq*4+0][arow] = av.x;
        As[akq*4+1][arow] = av.y;
        As[akq*4+2][arow] = av.z;
        As[akq*4+3][arow] = av.w;
        *(float4*)&Bs[bkr][bn4*4] =
            *(const float4*)(B + (size_t)(kt + bkr) * N + n0 + bn4 * 4);
        __syncthreads();
        #pragma unroll
        for (int kk = 0; kk < 16; ++kk) {
            float4 a = *(const float4*)&As[kk][tm*4];
            float4 b = *(const float4*)&Bs[kk][tn*4];
            acc[0][0] += a.x*b.x; acc[0][1] += a.x*b.y; acc[0][2] += a.x*b.z; acc[0][3] += a.x*b.w;
            acc[1][0] += a.y*b.x; acc[1][1] += a.y*b.y; acc[1][2] += a.y*b.z; acc[1][3] += a.y*b.w;
            acc[2][0] += a.z*b.x; acc[2][1] += a.z*b.y; acc[2][2] += a.z*b.z; acc[2][3] += a.z*b.w;
            acc[3][0] += a.w*b.x; acc[3][1] += a.w*b.y; acc[3][2] += a.w*b.z; acc[3][3] += a.w*b.w;
        }
    }
    #pragma unroll
    for (int i = 0; i < 4; ++i) {
        float4 o = make_float4(acc[i][0], acc[i][1], acc[i][2], acc[i][3]);
        *(float4*)(C + (size_t)(m0 + tm*4 + i) * N + n0 + tn*4) = o;
    }
}

// ---------------------------------------------------------------------------
// Score stats: per (head, 4 query rows) compute full 2048-key softmax stats.
// #pragma unroll 1 on constant-trip chunk loops: prevents the full-unroll ->
// register-spill catastrophe observed in round-1 attn_k (6.6 GB scratch).
// ---------------------------------------------------------------------------
__global__ __launch_bounds__(256) void score_stats(const float* __restrict__ q,
                                                   const float* __restrict__ k,
                                                   float* __restrict__ ent,
                                                   float* __restrict__ mxa,
                                                   float* __restrict__ infl) {
    __shared__ float  sc[4][SEQ];      // 32 KB
    __shared__ float  ks[64][68];      // 17.4 KB
    __shared__ float4 qs[4][16];       // 1 KB
    __shared__ float  mrow[4], lrow[4];
    int h  = blockIdx.x;
    int q0 = blockIdx.y * 4;
    int t  = threadIdx.x;
    {   // load 4 q rows
        int r = t >> 6, d = t & 63;
        ((float*)&qs[r][0])[d] = q[(size_t)(q0 + r) * HID + h * HD + d];
    }
    int j = t & 63, r = t >> 6;
    #pragma unroll 1
    for (int c = 0; c < SEQ / 64; ++c) {
        __syncthreads();
        #pragma unroll
        for (int wj = 0; wj < 4; ++wj) {          // stage 64 keys x 64 dims
            int idx = wj * 256 + t;               // float4 index 0..1023
            int key = idx >> 4, d4 = idx & 15;
            *(float4*)&ks[key][d4*4] =
                *(const float4*)(k + (size_t)(c*64 + key) * HID + h * HD + d4*4);
        }
        __syncthreads();
        float s = 0.f;
        #pragma unroll
        for (int d4 = 0; d4 < 16; ++d4) {
            float4 a = qs[r][d4];
            float4 b = *(const float4*)&ks[j][d4*4];
            s += a.x*b.x + a.y*b.y + a.z*b.z + a.w*b.w;
        }
        sc[r][c*64 + j] = s * SCALE;
    }
    __syncthreads();
    // phase B: wave w handles row w
    int w = t >> 6, lane = t & 63;
    float m = -1e30f;
    #pragma unroll 1
    for (int i = 0; i < SEQ/64; ++i) m = fmaxf(m, sc[w][lane + 64*i]);
    #pragma unroll
    for (int off = 32; off; off >>= 1) m = fmaxf(m, __shfl_xor(m, off));
    float l = 0.f;
    #pragma unroll 1
    for (int i = 0; i < SEQ/64; ++i) l += expf(sc[w][lane + 64*i] - m);
    #pragma unroll
    for (int off = 32; off; off >>= 1) l += __shfl_xor(l, off);
    float e = 0.f;
    #pragma unroll 1
    for (int i = 0; i < SEQ/64; ++i) {
        float p = expf(sc[w][lane + 64*i] - m) / l;
        e -= p * logf(fmaxf(p, 1e-8f));
    }
    #pragma unroll
    for (int off = 32; off; off >>= 1) e += __shfl_xor(e, off);
    if (lane == 0) {
        ent[h*SEQ + q0 + w] = e;
        mxa[h*SEQ + q0 + w] = 1.f / l;   // max prob = exp(m-m)/l
        mrow[w] = m; lrow[w] = l;
    }
    __syncthreads();
    // phase C: column influence (sum over this block's 4 rows)
    float m0v = mrow[0], m1v = mrow[1], m2v = mrow[2], m3v = mrow[3];
    float l0v = lrow[0], l1v = lrow[1], l2v = lrow[2], l3v = lrow[3];
    #pragma unroll 1
    for (int i = 0; i < SEQ/256; ++i) {
        int jj = t + 256*i;
        float a = expf(sc[0][jj]-m0v)/l0v + expf(sc[1][jj]-m1v)/l1v
                + expf(sc[2][jj]-m2v)/l2v + expf(sc[3][jj]-m3v)/l3v;
        atomicAdd(&infl[jj], a);
    }
}

__global__ __launch_bounds__(256) void importance_k(const float* __restrict__ ent,
                                                    const float* __restrict__ mxa,
                                                    const float* __restrict__ infl,
                                                    float* __restrict__ imp) {
    int s = blockIdx.x * 256 + threadIdx.x;
    float es = 0.f, ms = 0.f;
    #pragma unroll
    for (int h = 0; h < NH; ++h) { es += ent[h*SEQ + s]; ms += mxa[h*SEQ + s]; }
    imp[s] = (-0.4f*es + 0.3f*ms + 0.3f*infl[s]) * (1.f/16.f);
}

// Deterministic top-k by rank counting (matches lax.top_k set semantics;
// attention is permutation-invariant over the selected set).
__global__ __launch_bounds__(256) void topk_k(const float* __restrict__ imp,
                                              int* __restrict__ hh) {
    __shared__ float si[SEQ];
    int t = threadIdx.x, s = blockIdx.x * 256 + t;
    for (int i = t; i < SEQ; i += 256) si[i] = imp[i];
    __syncthreads();
    float v = si[s];
    int rank = 0;
    #pragma unroll 1
    for (int i = 0; i < SEQ; ++i) {
        float u = si[i];
        rank += (u > v) || (u == v && i < s);
    }
    if (rank < NKH) hh[rank] = s;
}

// per-(h,s) L2 norm of a 64-dim head vector (one wave each)
__global__ __launch_bounds__(256) void norms_k(const float* __restrict__ x,
                                               float* __restrict__ n) {
    int t = threadIdx.x;
    int wid = blockIdx.x * 4 + (t >> 6);    // 0..32767
    int lane = t & 63;
    int h = wid >> 11, s = wid & 2047;
    float v = x[(size_t)s * HID + h * HD + lane];
    float ss = v * v;
    #pragma unroll
    for (int off = 32; off; off >>= 1) ss += __shfl_xor(ss, off);
    if (lane == 0) n[h*SEQ + s] = sqrtf(ss);
}

// in-place softmax over SEQ per head (one block per head)
__global__ __launch_bounds__(256) void softw_k(float* __restrict__ n) {
    __shared__ float red[8];
    int h = blockIdx.x, t = threadIdx.x, lane = t & 63, w = t >> 6;
    float* nh = n + (size_t)h * SEQ;
    float m = -1e30f;
    for (int i = t; i < SEQ; i += 256) m = fmaxf(m, nh[i]);
    #pragma unroll
    for (int off = 32; off; off >>= 1) m = fmaxf(m, __shfl_xor(m, off));
    if (lane == 0) red[w] = m;
    __syncthreads();
    m = fmaxf(fmaxf(red[0], red[1]), fmaxf(red[2], red[3]));
    float z = 0.f;
    for (int i = t; i < SEQ; i += 256) z += expf(nh[i] - m);
    #pragma unroll
    for (int off = 32; off; off >>= 1) z += __shfl_xor(z, off);
    if (lane == 0) red[4 + w] = z;
    __syncthreads();
    z = red[4] + red[5] + red[6] + red[7];
    for (int i = t; i < SEQ; i += 256) nh[i] = expf(nh[i] - m) / z;
}

// group-4 weighted pooling -> compressed keys/values at cat[h][204+l][:]
__global__ __launch_bounds__(256) void pool_k(const float* __restrict__ src,
                                              const float* __restrict__ w,
                                              float* __restrict__ cat) {
    int g = blockIdx.x * 256 + threadIdx.x;   // 16*512*64
    int d = g & 63, rest = g >> 6;
    int l = rest & 511, h = rest >> 9;
    const float* wp = w + (size_t)h * SEQ + l * 4;
    float w0 = wp[0], w1 = wp[1], w2 = wp[2], w3 = wp[3];
    float wsum = w0 + w1 + w2 + w3 + 1e-8f;
    size_t base = (size_t)(l*4) * HID + h * HD + d;
    float val = src[base]*w0 + src[base+HID]*w1 + src[base+2*HID]*w2 + src[base+3*HID]*w3;
    cat[((size_t)h * NCATP + NKH + l) * HD + d] = val / wsum;
}

// gather heavy-hitter k/v rows into cat[h][0..203][:]
__global__ __launch_bounds__(256) void gather_k(const float* __restrict__ k,
                                                const float* __restrict__ v,
                                                const int* __restrict__ hh,
                                                float* __restrict__ kcat,
                                                float* __restrict__ vcat) {
    int g = blockIdx.x * 256 + threadIdx.x;   // 16*204*64 = 208896 exactly
    int d = g & 63, rest = g >> 6;
    int i = rest % NKH, h = rest / NKH;
    int s = hh[i];
    size_t src = (size_t)s * HID + h * HD + d;
    size_t dst = ((size_t)h * NCATP + i) * HD + d;
    kcat[dst] = k[src];
    vcat[dst] = v[src];
}

// zero the 52 pad keys per head so PV multiplies prob=0 by finite values
__global__ __launch_bounds__(256) void padzero_k(float* __restrict__ kcat,
                                                 float* __restrict__ vcat) {
    int g = blockIdx.x * 256 + threadIdx.x;   // 16*52*64 = 53248 -> 208 blocks
    if (g >= NH * (NCATP - NCAT) * HD) return;
    int d = g & 63, rest = g >> 6;
    int i = rest % (NCATP - NCAT), h = rest / (NCATP - NCAT);
    size_t dst = ((size_t)h * NCATP + NCAT + i) * HD + d;
    kcat[dst] = 0.f;
    vcat[dst] = 0.f;
}

// ---------------------------------------------------------------------------
// Final attention v2: block = (head, 8 queries), 768 padded keys.
// All chunk loops pinned with #pragma unroll 1 (anti-spill), K row cached in
// 16 float4 regs and reused across 2 q-rows, pad keys masked to -1e30.
// ---------------------------------------------------------------------------
__global__ __launch_bounds__(256) void attn_k(const float* __restrict__ q,
                                              const float* __restrict__ kcat,
                                              const float* __restrict__ vcat,
                                              float* __restrict__ ao) {
    __shared__ float sc[8][NCATP];    // 24 KB scores/probs
    __shared__ float tile[64][68];    // 17.4 KB staged K or V chunk
    __shared__ float qs[8][68];       // 2.2 KB
    int h = blockIdx.x, q0 = blockIdx.y * 8;
    int t = threadIdx.x;
    {   // load 8 q rows as float2 per thread
        int r = t >> 5, d2 = t & 31;
        *(float2*)&qs[r][d2*2] =
            *(const float2*)(q + (size_t)(q0 + r) * HID + h * HD + d2*2);
    }
    const float* kh = kcat + (size_t)h * NCATP * HD;
    const float* vh = vcat + (size_t)h * NCATP * HD;
    int j = t & 63, w = t >> 6;

    // ---- phase A: scores ----
    #pragma unroll 1
    for (int c = 0; c < NCATP/64; ++c) {
        __syncthreads();
        #pragma unroll
        for (int wj = 0; wj < 4; ++wj) {
            int idx = wj * 256 + t;
            int key = idx >> 4, d4 = idx & 15;
            *(float4*)&tile[key][d4*4] =
                *(const float4*)(kh + (size_t)(c*64 + key) * HD + d4*4);
        }
        __syncthreads();
        float4 kr[16];
        #pragma unroll
        for (int d4 = 0; d4 < 16; ++d4) kr[d4] = *(const float4*)&tile[j][d4*4];
        #pragma unroll
        for (int rr = 0; rr < 2; ++rr) {
            int r = w + rr*4;
            float s = 0.f;
            #pragma unroll
            for (int d4 = 0; d4 < 16; ++d4) {
                float4 a = *(const float4*)&qs[r][d4*4];   // wave-uniform bcast
                s += a.x*kr[d4].x + a.y*kr[d4].y + a.z*kr[d4].z + a.w*kr[d4].w;
            }
            sc[r][c*64 + j] = s * SCALE;
        }
    }
    __syncthreads();
    // mask pad keys 716..767 to -inf
    for (int i = t; i < 8*64; i += 256) {
        int r = i >> 6, jj = 704 + (i & 63);
        if (jj >= NCAT) sc[r][jj] = -1e30f;
    }
    __syncthreads();

    // ---- phase B: softmax, wave w handles rows w and w+4 ----
    int lane = t & 63;
    #pragma unroll 1
    for (int rr = 0; rr < 2; ++rr) {
        int r = w + rr*4;
        float m = -1e30f;
        #pragma unroll 1
        for (int i = lane; i < NCATP; i += 64) m = fmaxf(m, sc[r][i]);
        #pragma unroll
        for (int off = 32; off; off >>= 1) m = fmaxf(m, __shfl_xor(m, off));
        float l = 0.f;
        #pragma unroll 1
        for (int i = lane; i < NCATP; i += 64) l += expf(sc[r][i] - m);
        #pragma unroll
        for (int off = 32; off; off >>= 1) l += __shfl_xor(l, off);
        float inv = 1.f / l;
        #pragma unroll 1
        for (int i = lane; i < NCATP; i += 64) sc[r][i] = expf(sc[r][i] - m) * inv;
    }

    // ---- phase C: PV, thread -> (row r = t>>5, float2 dims) ----
    int d2 = t & 31, r = t >> 5;
    float2 acc = make_float2(0.f, 0.f);
    #pragma unroll 1
    for (int c = 0; c < NCATP/64; ++c) {
        __syncthreads();
        #pragma unroll
        for (int wj = 0; wj < 4; ++wj) {
            int idx = wj * 256 + t;
            int key = idx >> 4, d4 = idx & 15;
            *(float4*)&tile[key][d4*4] =
                *(const float4*)(vh + (size_t)(c*64 + key) * HD + d4*4);
        }
        __syncthreads();
        #pragma unroll 8
        for (int jj = 0; jj < 64; ++jj) {
            float pj = sc[r][c*64 + jj];
            float2 vv = *(const float2*)&tile[jj][d2*2];
            acc.x += pj * vv.x;
            acc.y += pj * vv.y;
        }
    }
    *(float2*)(ao + (size_t)(q0 + r) * HID + h * HD + d2*2) = acc;
}

// ---------------------------------------------------------------------------
extern "C" void kernel_launch(void* const* d_in, const int* in_sizes, int n_in,
                              void* d_out, int out_size, void* d_ws, size_t ws_size,
                              hipStream_t stream) {
    const float* x  = (const float*)d_in[0];
    const float* Wq = (const float*)d_in[1];
    const float* Wk = (const float*)d_in[2];
    const float* Wv = (const float*)d_in[3];
    const float* Wo = (const float*)d_in[4];
    float* out = (float*)d_out;

    float* ws   = (float*)d_ws;                 // ~40 MB total
    float* q    = ws;                           // 2048*1024
    float* k    = q    + (size_t)SEQ*HID;
    float* v    = k    + (size_t)SEQ*HID;
    float* ao   = v    + (size_t)SEQ*HID;
    float* ent  = ao   + (size_t)SEQ*HID;       // 16*2048
    float* mxa  = ent  + NH*SEQ;
    float* infl = mxa  + NH*SEQ;                // 2048
    float* imp  = infl + SEQ;                   // 2048
    int*   hh   = (int*)(imp + SEQ);            // 256 slots (204 used)
    float* wk   = (float*)(hh + 256);           // 16*2048
    float* wv   = wk   + NH*SEQ;
    float* kcat = wv   + NH*SEQ;                // 16*768*64
    float* vcat = kcat + (size_t)NH*NCATP*HD;

    dim3 gB(16, 32);   // N/64, M/64 for 2048x1024x1024
    gemm_f32<<<gB, 256, 0, stream>>>(x, Wq, q, SEQ, HID, HID);
    gemm_f32<<<gB, 256, 0, stream>>>(x, Wk, k, SEQ, HID, HID);
    gemm_f32<<<gB, 256, 0, stream>>>(x, Wv, v, SEQ, HID, HID);

    hipMemsetAsync(infl, 0, SEQ * sizeof(float), stream);
    score_stats<<<dim3(NH, SEQ/4), 256, 0, stream>>>(q, k, ent, mxa, infl);
    importance_k<<<SEQ/256, 256, 0, stream>>>(ent, mxa, infl, imp);
    topk_k<<<SEQ/256, 256, 0, stream>>>(imp, hh);

    norms_k<<<NH*SEQ/4, 256, 0, stream>>>(k, wk);
    norms_k<<<NH*SEQ/4, 256, 0, stream>>>(v, wv);
    softw_k<<<NH, 256, 0, stream>>>(wk);
    softw_k<<<NH, 256, 0, stream>>>(wv);
    pool_k<<<NH*LCOMP*HD/256, 256, 0, stream>>>(k, wk, kcat);
    pool_k<<<NH*LCOMP*HD/256, 256, 0, stream>>>(v, wv, vcat);
    padzero_k<<<208, 256, 0, stream>>>(kcat, vcat);
    gather_k<<<NH*NKH*HD/256, 256, 0, stream>>>(k, v, hh, kcat, vcat);

    attn_k<<<dim3(NH, SEQ/8), 256, 0, stream>>>(q, kcat, vcat, ao);
    gemm_f32<<<gB, 256, 0, stream>>>(ao, Wo, out, SEQ, HID, HID);
}

// Round 3
// 975.295 us; speedup vs baseline: 6.4318x; 1.3450x over previous
//
#include <hip/hip_runtime.h>
#include <math.h>

#define SEQ   2048
#define HID   1024
#define NH    16
#define HD    64
#define NKH   204          // heavy hitters = int(2048*0.1)
#define LCOMP 512          // compressed length = 2048/4
#define NCAT  716          // 204 + 512
#define NCATP 768          // padded to multiple of 64 (52 pad keys)
#define SCALE 0.125f       // 1/sqrt(64)

typedef __attribute__((ext_vector_type(8))) short short8;   // 8 bf16 (4 VGPRs)
typedef __attribute__((ext_vector_type(4))) float f32x4;    // MFMA accumulator

// ---- bf16 split helpers (RNE) -------------------------------------------
__device__ __forceinline__ short f2bf(float f) {
    unsigned u = __builtin_bit_cast(unsigned, f);
    u += 0x7FFFu + ((u >> 16) & 1u);
    return (short)(u >> 16);
}
__device__ __forceinline__ float bf2f(short h) {
    unsigned u = ((unsigned)(unsigned short)h) << 16;
    return __builtin_bit_cast(float, u);
}
// split 8 consecutive floats into hi/lo bf16 fragments
__device__ __forceinline__ void split8(float4 a, float4 b, short8& hi, short8& lo) {
    float v0 = a.x, v1 = a.y, v2 = a.z, v3 = a.w;
    float v4 = b.x, v5 = b.y, v6 = b.z, v7 = b.w;
    short h;
    h = f2bf(v0); hi[0] = h; lo[0] = f2bf(v0 - bf2f(h));
    h = f2bf(v1); hi[1] = h; lo[1] = f2bf(v1 - bf2f(h));
    h = f2bf(v2); hi[2] = h; lo[2] = f2bf(v2 - bf2f(h));
    h = f2bf(v3); hi[3] = h; lo[3] = f2bf(v3 - bf2f(h));
    h = f2bf(v4); hi[4] = h; lo[4] = f2bf(v4 - bf2f(h));
    h = f2bf(v5); hi[5] = h; lo[5] = f2bf(v5 - bf2f(h));
    h = f2bf(v6); hi[6] = h; lo[6] = f2bf(v6 - bf2f(h));
    h = f2bf(v7); hi[7] = h; lo[7] = f2bf(v7 - bf2f(h));
}

// ---------------------------------------------------------------------------
// Tiled f32 GEMM: C[M,N] = A[M,K] @ B[K,N].  64x64 tile, 256 thr, 4x4 micro.
// ---------------------------------------------------------------------------
__global__ __launch_bounds__(256) void gemm_f32(const float* __restrict__ A,
                                                const float* __restrict__ B,
                                                float* __restrict__ C,
                                                int M, int N, int K) {
    __shared__ float As[16][68];
    __shared__ float Bs[16][68];
    int t  = threadIdx.x;
    int tn = t & 15, tm = t >> 4;
    int m0 = blockIdx.y * 64, n0 = blockIdx.x * 64;
    int arow = t >> 2, akq = t & 3;
    int bkr  = t >> 4, bn4 = t & 15;
    float acc[4][4] = {};
    for (int kt = 0; kt < K; kt += 16) {
        __syncthreads();
        float4 av = *(const float4*)(A + (size_t)(m0 + arow) * K + kt + akq * 4);
        As[akq*4+0][arow] = av.x;
        As[akq*4+1][arow] = av.y;
        As[akq*4+2][arow] = av.z;
        As[akq*4+3][arow] = av.w;
        *(float4*)&Bs[bkr][bn4*4] =
            *(const float4*)(B + (size_t)(kt + bkr) * N + n0 + bn4 * 4);
        __syncthreads();
        #pragma unroll
        for (int kk = 0; kk < 16; ++kk) {
            float4 a = *(const float4*)&As[kk][tm*4];
            float4 b = *(const float4*)&Bs[kk][tn*4];
            acc[0][0] += a.x*b.x; acc[0][1] += a.x*b.y; acc[0][2] += a.x*b.z; acc[0][3] += a.x*b.w;
            acc[1][0] += a.y*b.x; acc[1][1] += a.y*b.y; acc[1][2] += a.y*b.z; acc[1][3] += a.y*b.w;
            acc[2][0] += a.z*b.x; acc[2][1] += a.z*b.y; acc[2][2] += a.z*b.z; acc[2][3] += a.z*b.w;
            acc[3][0] += a.w*b.x; acc[3][1] += a.w*b.y; acc[3][2] += a.w*b.z; acc[3][3] += a.w*b.w;
        }
    }
    #pragma unroll
    for (int i = 0; i < 4; ++i) {
        float4 o = make_float4(acc[i][0], acc[i][1], acc[i][2], acc[i][3]);
        *(float4*)(C + (size_t)(m0 + tm*4 + i) * N + n0 + tn*4) = o;
    }
}

// ---------------------------------------------------------------------------
// Score stats via bf16x3 MFMA.  Block = (head, 16 q rows), 4 waves; wave w
// owns keys [w*512, w*512+512).  All 128 scores/lane live in VGPRs.
// mfma_f32_16x16x32_bf16 layouts (guide §3, m89/m91-verified):
//   A: m=lane&15, k=quad*8+j ; B: n=lane&15, k=quad*8+j ;
//   C/D: col=lane&15, row=quad*4+reg.
// ---------------------------------------------------------------------------
__global__ __launch_bounds__(256) void score_mfma(const float* __restrict__ q,
                                                  const float* __restrict__ k,
                                                  float* __restrict__ ent,
                                                  float* __restrict__ mxa,
                                                  float* __restrict__ infl) {
    __shared__ float redm[4][16], redl[4][16], rede[4][16];
    int h  = blockIdx.x;
    int m0 = blockIdx.y * 16;
    int t  = threadIdx.x;
    int lane = t & 63, w = t >> 6;
    int quad = lane >> 4, c16 = lane & 15;

    // ---- A fragments (q rows), held for the whole kernel ----
    const float* qp = q + (size_t)(m0 + c16) * HID + h * HD;
    short8 Ah0, Al0, Ah1, Al1;
    {
        float4 a0 = *(const float4*)(qp + quad*8);
        float4 a1 = *(const float4*)(qp + quad*8 + 4);
        float4 a2 = *(const float4*)(qp + 32 + quad*8);
        float4 a3 = *(const float4*)(qp + 32 + quad*8 + 4);
        split8(a0, a1, Ah0, Al0);
        split8(a2, a3, Ah1, Al1);
    }

    // ---- scores: 32 ntiles of 16 keys, 6 MFMAs each ----
    float sreg[32][4];
    #pragma unroll
    for (int nt = 0; nt < 32; ++nt) {
        int n0 = (w * 32 + nt) * 16;
        const float* kb = k + (size_t)(n0 + c16) * HID + h * HD;
        float4 b0 = *(const float4*)(kb + quad*8);
        float4 b1 = *(const float4*)(kb + quad*8 + 4);
        float4 b2 = *(const float4*)(kb + 32 + quad*8);
        float4 b3 = *(const float4*)(kb + 32 + quad*8 + 4);
        short8 Bh0, Bl0, Bh1, Bl1;
        split8(b0, b1, Bh0, Bl0);
        split8(b2, b3, Bh1, Bl1);
        f32x4 acc = {0.f, 0.f, 0.f, 0.f};
        acc = __builtin_amdgcn_mfma_f32_16x16x32_bf16(Ah0, Bh0, acc, 0, 0, 0);
        acc = __builtin_amdgcn_mfma_f32_16x16x32_bf16(Al0, Bh0, acc, 0, 0, 0);
        acc = __builtin_amdgcn_mfma_f32_16x16x32_bf16(Ah0, Bl0, acc, 0, 0, 0);
        acc = __builtin_amdgcn_mfma_f32_16x16x32_bf16(Ah1, Bh1, acc, 0, 0, 0);
        acc = __builtin_amdgcn_mfma_f32_16x16x32_bf16(Al1, Bh1, acc, 0, 0, 0);
        acc = __builtin_amdgcn_mfma_f32_16x16x32_bf16(Ah1, Bl1, acc, 0, 0, 0);
        #pragma unroll
        for (int i = 0; i < 4; ++i) sreg[nt][i] = acc[i] * SCALE;
    }

    // ---- row max over this wave's 512 cols ----
    float m[4];
    #pragma unroll
    for (int i = 0; i < 4; ++i) {
        float mm = -1e30f;
        #pragma unroll
        for (int nt = 0; nt < 32; ++nt) mm = fmaxf(mm, sreg[nt][i]);
        #pragma unroll
        for (int off = 1; off <= 8; off <<= 1) mm = fmaxf(mm, __shfl_xor(mm, off));
        m[i] = mm;
    }
    if (c16 == 0) {
        #pragma unroll
        for (int i = 0; i < 4; ++i) redm[w][quad*4 + i] = m[i];
    }
    __syncthreads();
    #pragma unroll
    for (int i = 0; i < 4; ++i) {
        int row = quad*4 + i;
        m[i] = fmaxf(fmaxf(redm[0][row], redm[1][row]),
                     fmaxf(redm[2][row], redm[3][row]));
    }

    // ---- l = sum exp(s - m) ----
    float l[4];
    #pragma unroll
    for (int i = 0; i < 4; ++i) {
        float ll = 0.f;
        #pragma unroll
        for (int nt = 0; nt < 32; ++nt) ll += expf(sreg[nt][i] - m[i]);
        #pragma unroll
        for (int off = 1; off <= 8; off <<= 1) ll += __shfl_xor(ll, off);
        l[i] = ll;
    }
    if (c16 == 0) {
        #pragma unroll
        for (int i = 0; i < 4; ++i) redl[w][quad*4 + i] = l[i];
    }
    __syncthreads();
    #pragma unroll
    for (int i = 0; i < 4; ++i) {
        int row = quad*4 + i;
        l[i] = redl[0][row] + redl[1][row] + redl[2][row] + redl[3][row];
    }
    if (w == 0 && c16 == 0) {
        #pragma unroll
        for (int i = 0; i < 4; ++i)
            mxa[h*SEQ + m0 + quad*4 + i] = 1.f / l[i];   // max prob
    }

    // ---- entropy + influence ----
    float inv[4];
    #pragma unroll
    for (int i = 0; i < 4; ++i) inv[i] = 1.f / l[i];
    float e[4] = {0.f, 0.f, 0.f, 0.f};
    #pragma unroll
    for (int nt = 0; nt < 32; ++nt) {
        float cs = 0.f;
        #pragma unroll
        for (int i = 0; i < 4; ++i) {
            float p = expf(sreg[nt][i] - m[i]) * inv[i];
            e[i] -= p * logf(fmaxf(p, 1e-8f));
            cs += p;
        }
        cs += __shfl_xor(cs, 16);
        cs += __shfl_xor(cs, 32);                 // all lanes: col sum over 16 rows
        if (lane < 16) atomicAdd(&infl[(w*32 + nt)*16 + lane], cs);
    }
    #pragma unroll
    for (int i = 0; i < 4; ++i) {
        #pragma unroll
        for (int off = 1; off <= 8; off <<= 1) e[i] += __shfl_xor(e[i], off);
    }
    if (c16 == 0) {
        #pragma unroll
        for (int i = 0; i < 4; ++i) rede[w][quad*4 + i] = e[i];
    }
    __syncthreads();
    if (w == 0 && c16 == 0) {
        #pragma unroll
        for (int i = 0; i < 4; ++i) {
            int row = quad*4 + i;
            ent[h*SEQ + m0 + row] =
                rede[0][row] + rede[1][row] + rede[2][row] + rede[3][row];
        }
    }
}

__global__ __launch_bounds__(256) void importance_k(const float* __restrict__ ent,
                                                    const float* __restrict__ mxa,
                                                    const float* __restrict__ infl,
                                                    float* __restrict__ imp) {
    int s = blockIdx.x * 256 + threadIdx.x;
    float es = 0.f, ms = 0.f;
    #pragma unroll
    for (int h = 0; h < NH; ++h) { es += ent[h*SEQ + s]; ms += mxa[h*SEQ + s]; }
    imp[s] = (-0.4f*es + 0.3f*ms + 0.3f*infl[s]) * (1.f/16.f);
}

// Deterministic top-k by rank counting (matches lax.top_k set semantics).
__global__ __launch_bounds__(256) void topk_k(const float* __restrict__ imp,
                                              int* __restrict__ hh) {
    __shared__ float si[SEQ];
    int t = threadIdx.x, s = blockIdx.x * 256 + t;
    for (int i = t; i < SEQ; i += 256) si[i] = imp[i];
    __syncthreads();
    float v = si[s];
    int rank = 0;
    #pragma unroll 1
    for (int i = 0; i < SEQ; ++i) {
        float u = si[i];
        rank += (u > v) || (u == v && i < s);
    }
    if (rank < NKH) hh[rank] = s;
}

// per-(h,s) L2 norm of a 64-dim head vector (one wave each)
__global__ __launch_bounds__(256) void norms_k(const float* __restrict__ x,
                                               float* __restrict__ n) {
    int t = threadIdx.x;
    int wid = blockIdx.x * 4 + (t >> 6);
    int lane = t & 63;
    int h = wid >> 11, s = wid & 2047;
    float v = x[(size_t)s * HID + h * HD + lane];
    float ss = v * v;
    #pragma unroll
    for (int off = 32; off; off >>= 1) ss += __shfl_xor(ss, off);
    if (lane == 0) n[h*SEQ + s] = sqrtf(ss);
}

// in-place softmax over SEQ per head (one block per head)
__global__ __launch_bounds__(256) void softw_k(float* __restrict__ n) {
    __shared__ float red[8];
    int h = blockIdx.x, t = threadIdx.x, lane = t & 63, w = t >> 6;
    float* nh = n + (size_t)h * SEQ;
    float m = -1e30f;
    for (int i = t; i < SEQ; i += 256) m = fmaxf(m, nh[i]);
    #pragma unroll
    for (int off = 32; off; off >>= 1) m = fmaxf(m, __shfl_xor(m, off));
    if (lane == 0) red[w] = m;
    __syncthreads();
    m = fmaxf(fmaxf(red[0], red[1]), fmaxf(red[2], red[3]));
    float z = 0.f;
    for (int i = t; i < SEQ; i += 256) z += expf(nh[i] - m);
    #pragma unroll
    for (int off = 32; off; off >>= 1) z += __shfl_xor(z, off);
    if (lane == 0) red[4 + w] = z;
    __syncthreads();
    z = red[4] + red[5] + red[6] + red[7];
    for (int i = t; i < SEQ; i += 256) nh[i] = expf(nh[i] - m) / z;
}

// group-4 weighted pooling -> compressed keys/values at cat[h][204+l][:]
__global__ __launch_bounds__(256) void pool_k(const float* __restrict__ src,
                                              const float* __restrict__ w,
                                              float* __restrict__ cat) {
    int g = blockIdx.x * 256 + threadIdx.x;
    int d = g & 63, rest = g >> 6;
    int l = rest & 511, h = rest >> 9;
    const float* wp = w + (size_t)h * SEQ + l * 4;
    float w0 = wp[0], w1 = wp[1], w2 = wp[2], w3 = wp[3];
    float wsum = w0 + w1 + w2 + w3 + 1e-8f;
    size_t base = (size_t)(l*4) * HID + h * HD + d;
    float val = src[base]*w0 + src[base+HID]*w1 + src[base+2*HID]*w2 + src[base+3*HID]*w3;
    cat[((size_t)h * NCATP + NKH + l) * HD + d] = val / wsum;
}

// gather heavy-hitter k/v rows into cat[h][0..203][:]
__global__ __launch_bounds__(256) void gather_k(const float* __restrict__ k,
                                                const float* __restrict__ v,
                                                const int* __restrict__ hh,
                                                float* __restrict__ kcat,
                                                float* __restrict__ vcat) {
    int g = blockIdx.x * 256 + threadIdx.x;
    int d = g & 63, rest = g >> 6;
    int i = rest % NKH, h = rest / NKH;
    int s = hh[i];
    size_t src = (size_t)s * HID + h * HD + d;
    size_t dst = ((size_t)h * NCATP + i) * HD + d;
    kcat[dst] = k[src];
    vcat[dst] = v[src];
}

// zero the 52 pad keys per head
__global__ __launch_bounds__(256) void padzero_k(float* __restrict__ kcat,
                                                 float* __restrict__ vcat) {
    int g = blockIdx.x * 256 + threadIdx.x;
    if (g >= NH * (NCATP - NCAT) * HD) return;
    int d = g & 63, rest = g >> 6;
    int i = rest % (NCATP - NCAT), h = rest / (NCATP - NCAT);
    size_t dst = ((size_t)h * NCATP + NCAT + i) * HD + d;
    kcat[dst] = 0.f;
    vcat[dst] = 0.f;
}

// ---------------------------------------------------------------------------
// Final attention: block = (head, 8 queries), 768 padded keys.
// ---------------------------------------------------------------------------
__global__ __launch_bounds__(256) void attn_k(const float* __restrict__ q,
                                              const float* __restrict__ kcat,
                                              const float* __restrict__ vcat,
                                              float* __restrict__ ao) {
    __shared__ float sc[8][NCATP];
    __shared__ float tile[64][68];
    __shared__ float qs[8][68];
    int h = blockIdx.x, q0 = blockIdx.y * 8;
    int t = threadIdx.x;
    {
        int r = t >> 5, d2 = t & 31;
        *(float2*)&qs[r][d2*2] =
            *(const float2*)(q + (size_t)(q0 + r) * HID + h * HD + d2*2);
    }
    const float* kh = kcat + (size_t)h * NCATP * HD;
    const float* vh = vcat + (size_t)h * NCATP * HD;
    int j = t & 63, w = t >> 6;

    #pragma unroll 1
    for (int c = 0; c < NCATP/64; ++c) {
        __syncthreads();
        #pragma unroll
        for (int wj = 0; wj < 4; ++wj) {
            int idx = wj * 256 + t;
            int key = idx >> 4, d4 = idx & 15;
            *(float4*)&tile[key][d4*4] =
                *(const float4*)(kh + (size_t)(c*64 + key) * HD + d4*4);
        }
        __syncthreads();
        float4 kr[16];
        #pragma unroll
        for (int d4 = 0; d4 < 16; ++d4) kr[d4] = *(const float4*)&tile[j][d4*4];
        #pragma unroll
        for (int rr = 0; rr < 2; ++rr) {
            int r = w + rr*4;
            float s = 0.f;
            #pragma unroll
            for (int d4 = 0; d4 < 16; ++d4) {
                float4 a = *(const float4*)&qs[r][d4*4];
                s += a.x*kr[d4].x + a.y*kr[d4].y + a.z*kr[d4].z + a.w*kr[d4].w;
            }
            sc[r][c*64 + j] = s * SCALE;
        }
    }
    __syncthreads();
    for (int i = t; i < 8*64; i += 256) {
        int r = i >> 6, jj = 704 + (i & 63);
        if (jj >= NCAT) sc[r][jj] = -1e30f;
    }
    __syncthreads();

    int lane = t & 63;
    #pragma unroll 1
    for (int rr = 0; rr < 2; ++rr) {
        int r = w + rr*4;
        float m = -1e30f;
        #pragma unroll 1
        for (int i = lane; i < NCATP; i += 64) m = fmaxf(m, sc[r][i]);
        #pragma unroll
        for (int off = 32; off; off >>= 1) m = fmaxf(m, __shfl_xor(m, off));
        float l = 0.f;
        #pragma unroll 1
        for (int i = lane; i < NCATP; i += 64) l += expf(sc[r][i] - m);
        #pragma unroll
        for (int off = 32; off; off >>= 1) l += __shfl_xor(l, off);
        float inv = 1.f / l;
        #pragma unroll 1
        for (int i = lane; i < NCATP; i += 64) sc[r][i] = expf(sc[r][i] - m) * inv;
    }

    int d2 = t & 31, r = t >> 5;
    float2 acc = make_float2(0.f, 0.f);
    #pragma unroll 1
    for (int c = 0; c < NCATP/64; ++c) {
        __syncthreads();
        #pragma unroll
        for (int wj = 0; wj < 4; ++wj) {
            int idx = wj * 256 + t;
            int key = idx >> 4, d4 = idx & 15;
            *(float4*)&tile[key][d4*4] =
                *(const float4*)(vh + (size_t)(c*64 + key) * HD + d4*4);
        }
        __syncthreads();
        #pragma unroll 8
        for (int jj = 0; jj < 64; ++jj) {
            float pj = sc[r][c*64 + jj];
            float2 vv = *(const float2*)&tile[jj][d2*2];
            acc.x += pj * vv.x;
            acc.y += pj * vv.y;
        }
    }
    *(float2*)(ao + (size_t)(q0 + r) * HID + h * HD + d2*2) = acc;
}

// ---------------------------------------------------------------------------
extern "C" void kernel_launch(void* const* d_in, const int* in_sizes, int n_in,
                              void* d_out, int out_size, void* d_ws, size_t ws_size,
                              hipStream_t stream) {
    const float* x  = (const float*)d_in[0];
    const float* Wq = (const float*)d_in[1];
    const float* Wk = (const float*)d_in[2];
    const float* Wv = (const float*)d_in[3];
    const float* Wo = (const float*)d_in[4];
    float* out = (float*)d_out;

    float* ws   = (float*)d_ws;
    float* q    = ws;
    float* k    = q    + (size_t)SEQ*HID;
    float* v    = k    + (size_t)SEQ*HID;
    float* ao   = v    + (size_t)SEQ*HID;
    float* ent  = ao   + (size_t)SEQ*HID;
    float* mxa  = ent  + NH*SEQ;
    float* infl = mxa  + NH*SEQ;
    float* imp  = infl + SEQ;
    int*   hh   = (int*)(imp + SEQ);
    float* wk   = (float*)(hh + 256);
    float* wv   = wk   + NH*SEQ;
    float* kcat = wv   + NH*SEQ;
    float* vcat = kcat + (size_t)NH*NCATP*HD;

    dim3 gB(16, 32);
    gemm_f32<<<gB, 256, 0, stream>>>(x, Wq, q, SEQ, HID, HID);
    gemm_f32<<<gB, 256, 0, stream>>>(x, Wk, k, SEQ, HID, HID);
    gemm_f32<<<gB, 256, 0, stream>>>(x, Wv, v, SEQ, HID, HID);

    hipMemsetAsync(infl, 0, SEQ * sizeof(float), stream);
    score_mfma<<<dim3(NH, SEQ/16), 256, 0, stream>>>(q, k, ent, mxa, infl);
    importance_k<<<SEQ/256, 256, 0, stream>>>(ent, mxa, infl, imp);
    topk_k<<<SEQ/256, 256, 0, stream>>>(imp, hh);

    norms_k<<<NH*SEQ/4, 256, 0, stream>>>(k, wk);
    norms_k<<<NH*SEQ/4, 256, 0, stream>>>(v, wv);
    softw_k<<<NH, 256, 0, stream>>>(wk);
    softw_k<<<NH, 256, 0, stream>>>(wv);
    pool_k<<<NH*LCOMP*HD/256, 256, 0, stream>>>(k, wk, kcat);
    pool_k<<<NH*LCOMP*HD/256, 256, 0, stream>>>(v, wv, vcat);
    padzero_k<<<208, 256, 0, stream>>>(kcat, vcat);
    gather_k<<<NH*NKH*HD/256, 256, 0, stream>>>(k, v, hh, kcat, vcat);

    attn_k<<<dim3(NH, SEQ/8), 256, 0, stream>>>(q, kcat, vcat, ao);
    gemm_f32<<<gB, 256, 0, stream>>>(ao, Wo, out, SEQ, HID, HID);
}

// Round 4
// 777.685 us; speedup vs baseline: 8.0661x; 1.2541x over previous
//
#include <hip/hip_runtime.h>
#include <math.h>

#define SEQ   2048
#define HID   1024
#define NH    16
#define HD    64
#define NKH   204          // heavy hitters = int(2048*0.1)
#define LCOMP 512          // compressed length = 2048/4
#define NCAT  716          // 204 + 512
#define NCATP 768          // padded to multiple of 64 (52 pad keys)
#define SCALE 0.125f       // 1/sqrt(64)

typedef __attribute__((ext_vector_type(8))) short short8;   // 8 bf16 (4 VGPRs)
typedef __attribute__((ext_vector_type(4))) float f32x4;    // MFMA accumulator

// ---- bf16 split helpers (RNE) -------------------------------------------
__device__ __forceinline__ short f2bf(float f) {
    unsigned u = __builtin_bit_cast(unsigned, f);
    u += 0x7FFFu + ((u >> 16) & 1u);
    return (short)(u >> 16);
}
__device__ __forceinline__ float bf2f(short h) {
    unsigned u = ((unsigned)(unsigned short)h) << 16;
    return __builtin_bit_cast(float, u);
}
// split 8 consecutive floats into hi/lo bf16 fragments
__device__ __forceinline__ void split8(float4 a, float4 b, short8& hi, short8& lo) {
    float v0 = a.x, v1 = a.y, v2 = a.z, v3 = a.w;
    float v4 = b.x, v5 = b.y, v6 = b.z, v7 = b.w;
    short h;
    h = f2bf(v0); hi[0] = h; lo[0] = f2bf(v0 - bf2f(h));
    h = f2bf(v1); hi[1] = h; lo[1] = f2bf(v1 - bf2f(h));
    h = f2bf(v2); hi[2] = h; lo[2] = f2bf(v2 - bf2f(h));
    h = f2bf(v3); hi[3] = h; lo[3] = f2bf(v3 - bf2f(h));
    h = f2bf(v4); hi[4] = h; lo[4] = f2bf(v4 - bf2f(h));
    h = f2bf(v5); hi[5] = h; lo[5] = f2bf(v5 - bf2f(h));
    h = f2bf(v6); hi[6] = h; lo[6] = f2bf(v6 - bf2f(h));
    h = f2bf(v7); hi[7] = h; lo[7] = f2bf(v7 - bf2f(h));
}

// ---------------------------------------------------------------------------
// Tiled f32 GEMM: C[M,N] = A[M,K] @ B[K,N].  64x64 tile, 256 thr, 4x4 micro.
// ---------------------------------------------------------------------------
__global__ __launch_bounds__(256) void gemm_f32(const float* __restrict__ A,
                                                const float* __restrict__ B,
                                                float* __restrict__ C,
                                                int M, int N, int K) {
    __shared__ float As[16][68];
    __shared__ float Bs[16][68];
    int t  = threadIdx.x;
    int tn = t & 15, tm = t >> 4;
    int m0 = blockIdx.y * 64, n0 = blockIdx.x * 64;
    int arow = t >> 2, akq = t & 3;
    int bkr  = t >> 4, bn4 = t & 15;
    float acc[4][4] = {};
    for (int kt = 0; kt < K; kt += 16) {
        __syncthreads();
        float4 av = *(const float4*)(A + (size_t)(m0 + arow) * K + kt + akq * 4);
        As[akq*4+0][arow] = av.x;
        As[akq*4+1][arow] = av.y;
        As[akq*4+2][arow] = av.z;
        As[akq*4+3][arow] = av.w;
        *(float4*)&Bs[bkr][bn4*4] =
            *(const float4*)(B + (size_t)(kt + bkr) * N + n0 + bn4 * 4);
        __syncthreads();
        #pragma unroll
        for (int kk = 0; kk < 16; ++kk) {
            float4 a = *(const float4*)&As[kk][tm*4];
            float4 b = *(const float4*)&Bs[kk][tn*4];
            acc[0][0] += a.x*b.x; acc[0][1] += a.x*b.y; acc[0][2] += a.x*b.z; acc[0][3] += a.x*b.w;
            acc[1][0] += a.y*b.x; acc[1][1] += a.y*b.y; acc[1][2] += a.y*b.z; acc[1][3] += a.y*b.w;
            acc[2][0] += a.z*b.x; acc[2][1] += a.z*b.y; acc[2][2] += a.z*b.z; acc[2][3] += a.z*b.w;
            acc[3][0] += a.w*b.x; acc[3][1] += a.w*b.y; acc[3][2] += a.w*b.z; acc[3][3] += a.w*b.w;
        }
    }
    #pragma unroll
    for (int i = 0; i < 4; ++i) {
        float4 o = make_float4(acc[i][0], acc[i][1], acc[i][2], acc[i][3]);
        *(float4*)(C + (size_t)(m0 + tm*4 + i) * N + n0 + tn*4) = o;
    }
}

// ---------------------------------------------------------------------------
// Score stats via bf16x3 MFMA.  Block = (head, 16 q rows), 4 waves; wave w
// owns keys [w*512, w*512+512).  All 128 scores/lane live in VGPRs.
//   A: m=lane&15, k=quad*8+j ; B: n=lane&15, k=quad*8+j ;
//   C/D: col=lane&15, row=quad*4+reg.
// ---------------------------------------------------------------------------
__global__ __launch_bounds__(256) void score_mfma(const float* __restrict__ q,
                                                  const float* __restrict__ k,
                                                  float* __restrict__ ent,
                                                  float* __restrict__ mxa,
                                                  float* __restrict__ infl) {
    __shared__ float redm[4][16], redl[4][16], rede[4][16];
    int h  = blockIdx.x;
    int m0 = blockIdx.y * 16;
    int t  = threadIdx.x;
    int lane = t & 63, w = t >> 6;
    int quad = lane >> 4, c16 = lane & 15;

    const float* qp = q + (size_t)(m0 + c16) * HID + h * HD;
    short8 Ah0, Al0, Ah1, Al1;
    {
        float4 a0 = *(const float4*)(qp + quad*8);
        float4 a1 = *(const float4*)(qp + quad*8 + 4);
        float4 a2 = *(const float4*)(qp + 32 + quad*8);
        float4 a3 = *(const float4*)(qp + 32 + quad*8 + 4);
        split8(a0, a1, Ah0, Al0);
        split8(a2, a3, Ah1, Al1);
    }

    float sreg[32][4];
    #pragma unroll
    for (int nt = 0; nt < 32; ++nt) {
        int n0 = (w * 32 + nt) * 16;
        const float* kb = k + (size_t)(n0 + c16) * HID + h * HD;
        float4 b0 = *(const float4*)(kb + quad*8);
        float4 b1 = *(const float4*)(kb + quad*8 + 4);
        float4 b2 = *(const float4*)(kb + 32 + quad*8);
        float4 b3 = *(const float4*)(kb + 32 + quad*8 + 4);
        short8 Bh0, Bl0, Bh1, Bl1;
        split8(b0, b1, Bh0, Bl0);
        split8(b2, b3, Bh1, Bl1);
        f32x4 acc = {0.f, 0.f, 0.f, 0.f};
        acc = __builtin_amdgcn_mfma_f32_16x16x32_bf16(Ah0, Bh0, acc, 0, 0, 0);
        acc = __builtin_amdgcn_mfma_f32_16x16x32_bf16(Al0, Bh0, acc, 0, 0, 0);
        acc = __builtin_amdgcn_mfma_f32_16x16x32_bf16(Ah0, Bl0, acc, 0, 0, 0);
        acc = __builtin_amdgcn_mfma_f32_16x16x32_bf16(Ah1, Bh1, acc, 0, 0, 0);
        acc = __builtin_amdgcn_mfma_f32_16x16x32_bf16(Al1, Bh1, acc, 0, 0, 0);
        acc = __builtin_amdgcn_mfma_f32_16x16x32_bf16(Ah1, Bl1, acc, 0, 0, 0);
        #pragma unroll
        for (int i = 0; i < 4; ++i) sreg[nt][i] = acc[i] * SCALE;
    }

    float m[4];
    #pragma unroll
    for (int i = 0; i < 4; ++i) {
        float mm = -1e30f;
        #pragma unroll
        for (int nt = 0; nt < 32; ++nt) mm = fmaxf(mm, sreg[nt][i]);
        #pragma unroll
        for (int off = 1; off <= 8; off <<= 1) mm = fmaxf(mm, __shfl_xor(mm, off));
        m[i] = mm;
    }
    if (c16 == 0) {
        #pragma unroll
        for (int i = 0; i < 4; ++i) redm[w][quad*4 + i] = m[i];
    }
    __syncthreads();
    #pragma unroll
    for (int i = 0; i < 4; ++i) {
        int row = quad*4 + i;
        m[i] = fmaxf(fmaxf(redm[0][row], redm[1][row]),
                     fmaxf(redm[2][row], redm[3][row]));
    }

    float l[4];
    #pragma unroll
    for (int i = 0; i < 4; ++i) {
        float ll = 0.f;
        #pragma unroll
        for (int nt = 0; nt < 32; ++nt) ll += expf(sreg[nt][i] - m[i]);
        #pragma unroll
        for (int off = 1; off <= 8; off <<= 1) ll += __shfl_xor(ll, off);
        l[i] = ll;
    }
    if (c16 == 0) {
        #pragma unroll
        for (int i = 0; i < 4; ++i) redl[w][quad*4 + i] = l[i];
    }
    __syncthreads();
    #pragma unroll
    for (int i = 0; i < 4; ++i) {
        int row = quad*4 + i;
        l[i] = redl[0][row] + redl[1][row] + redl[2][row] + redl[3][row];
    }
    if (w == 0 && c16 == 0) {
        #pragma unroll
        for (int i = 0; i < 4; ++i)
            mxa[h*SEQ + m0 + quad*4 + i] = 1.f / l[i];
    }

    float inv[4];
    #pragma unroll
    for (int i = 0; i < 4; ++i) inv[i] = 1.f / l[i];
    float e[4] = {0.f, 0.f, 0.f, 0.f};
    #pragma unroll
    for (int nt = 0; nt < 32; ++nt) {
        float cs = 0.f;
        #pragma unroll
        for (int i = 0; i < 4; ++i) {
            float p = expf(sreg[nt][i] - m[i]) * inv[i];
            e[i] -= p * logf(fmaxf(p, 1e-8f));
            cs += p;
        }
        cs += __shfl_xor(cs, 16);
        cs += __shfl_xor(cs, 32);
        if (lane < 16) atomicAdd(&infl[(w*32 + nt)*16 + lane], cs);
    }
    #pragma unroll
    for (int i = 0; i < 4; ++i) {
        #pragma unroll
        for (int off = 1; off <= 8; off <<= 1) e[i] += __shfl_xor(e[i], off);
    }
    if (c16 == 0) {
        #pragma unroll
        for (int i = 0; i < 4; ++i) rede[w][quad*4 + i] = e[i];
    }
    __syncthreads();
    if (w == 0 && c16 == 0) {
        #pragma unroll
        for (int i = 0; i < 4; ++i) {
            int row = quad*4 + i;
            ent[h*SEQ + m0 + row] =
                rede[0][row] + rede[1][row] + rede[2][row] + rede[3][row];
        }
    }
}

__global__ __launch_bounds__(256) void importance_k(const float* __restrict__ ent,
                                                    const float* __restrict__ mxa,
                                                    const float* __restrict__ infl,
                                                    float* __restrict__ imp) {
    int s = blockIdx.x * 256 + threadIdx.x;
    float es = 0.f, ms = 0.f;
    #pragma unroll
    for (int h = 0; h < NH; ++h) { es += ent[h*SEQ + s]; ms += mxa[h*SEQ + s]; }
    imp[s] = (-0.4f*es + 0.3f*ms + 0.3f*infl[s]) * (1.f/16.f);
}

// Deterministic top-k by rank counting (matches lax.top_k set semantics).
__global__ __launch_bounds__(256) void topk_k(const float* __restrict__ imp,
                                              int* __restrict__ hh) {
    __shared__ float si[SEQ];
    int t = threadIdx.x, s = blockIdx.x * 256 + t;
    for (int i = t; i < SEQ; i += 256) si[i] = imp[i];
    __syncthreads();
    float v = si[s];
    int rank = 0;
    #pragma unroll 1
    for (int i = 0; i < SEQ; ++i) {
        float u = si[i];
        rank += (u > v) || (u == v && i < s);
    }
    if (rank < NKH) hh[rank] = s;
}

// per-(h,s) L2 norm of a 64-dim head vector (one wave each)
__global__ __launch_bounds__(256) void norms_k(const float* __restrict__ x,
                                               float* __restrict__ n) {
    int t = threadIdx.x;
    int wid = blockIdx.x * 4 + (t >> 6);
    int lane = t & 63;
    int h = wid >> 11, s = wid & 2047;
    float v = x[(size_t)s * HID + h * HD + lane];
    float ss = v * v;
    #pragma unroll
    for (int off = 32; off; off >>= 1) ss += __shfl_xor(ss, off);
    if (lane == 0) n[h*SEQ + s] = sqrtf(ss);
}

// in-place softmax over SEQ per head (one block per head)
__global__ __launch_bounds__(256) void softw_k(float* __restrict__ n) {
    __shared__ float red[8];
    int h = blockIdx.x, t = threadIdx.x, lane = t & 63, w = t >> 6;
    float* nh = n + (size_t)h * SEQ;
    float m = -1e30f;
    for (int i = t; i < SEQ; i += 256) m = fmaxf(m, nh[i]);
    #pragma unroll
    for (int off = 32; off; off >>= 1) m = fmaxf(m, __shfl_xor(m, off));
    if (lane == 0) red[w] = m;
    __syncthreads();
    m = fmaxf(fmaxf(red[0], red[1]), fmaxf(red[2], red[3]));
    float z = 0.f;
    for (int i = t; i < SEQ; i += 256) z += expf(nh[i] - m);
    #pragma unroll
    for (int off = 32; off; off >>= 1) z += __shfl_xor(z, off);
    if (lane == 0) red[4 + w] = z;
    __syncthreads();
    z = red[4] + red[5] + red[6] + red[7];
    for (int i = t; i < SEQ; i += 256) nh[i] = expf(nh[i] - m) / z;
}

// group-4 weighted pooling of K -> pre-split bf16 [h][key][d]
__global__ __launch_bounds__(256) void poolk_k(const float* __restrict__ src,
                                               const float* __restrict__ w,
                                               unsigned short* __restrict__ hi,
                                               unsigned short* __restrict__ lo) {
    int g = blockIdx.x * 256 + threadIdx.x;
    int d = g & 63, rest = g >> 6;
    int l = rest & 511, h = rest >> 9;
    const float* wp = w + (size_t)h * SEQ + l * 4;
    float w0 = wp[0], w1 = wp[1], w2 = wp[2], w3 = wp[3];
    float wsum = w0 + w1 + w2 + w3 + 1e-8f;
    size_t base = (size_t)(l*4) * HID + h * HD + d;
    float val = (src[base]*w0 + src[base+HID]*w1 + src[base+2*HID]*w2 + src[base+3*HID]*w3) / wsum;
    size_t dst = ((size_t)h * NCATP + NKH + l) * HD + d;
    short hb = f2bf(val);
    hi[dst] = (unsigned short)hb;
    lo[dst] = (unsigned short)f2bf(val - bf2f(hb));
}

// group-4 weighted pooling of V -> pre-split bf16 TRANSPOSED [h][d][key]
__global__ __launch_bounds__(256) void poolv_k(const float* __restrict__ src,
                                               const float* __restrict__ w,
                                               unsigned short* __restrict__ hi,
                                               unsigned short* __restrict__ lo) {
    int g = blockIdx.x * 256 + threadIdx.x;
    int d = g & 63, rest = g >> 6;
    int l = rest & 511, h = rest >> 9;
    const float* wp = w + (size_t)h * SEQ + l * 4;
    float w0 = wp[0], w1 = wp[1], w2 = wp[2], w3 = wp[3];
    float wsum = w0 + w1 + w2 + w3 + 1e-8f;
    size_t base = (size_t)(l*4) * HID + h * HD + d;
    float val = (src[base]*w0 + src[base+HID]*w1 + src[base+2*HID]*w2 + src[base+3*HID]*w3) / wsum;
    size_t dst = ((size_t)h * HD + d) * NCATP + NKH + l;
    short hb = f2bf(val);
    hi[dst] = (unsigned short)hb;
    lo[dst] = (unsigned short)f2bf(val - bf2f(hb));
}

// gather heavy-hitter k/v rows -> pre-split bf16 (K direct, V transposed)
__global__ __launch_bounds__(256) void gather_k(const float* __restrict__ k,
                                                const float* __restrict__ v,
                                                const int* __restrict__ hh,
                                                unsigned short* __restrict__ khi,
                                                unsigned short* __restrict__ klo,
                                                unsigned short* __restrict__ vthi,
                                                unsigned short* __restrict__ vtlo) {
    int g = blockIdx.x * 256 + threadIdx.x;
    int d = g & 63, rest = g >> 6;
    int i = rest % NKH, h = rest / NKH;
    int s = hh[i];
    float kv = k[(size_t)s * HID + h * HD + d];
    float vv = v[(size_t)s * HID + h * HD + d];
    size_t kd = ((size_t)h * NCATP + i) * HD + d;
    size_t vd = ((size_t)h * HD + d) * NCATP + i;
    short hb = f2bf(kv);
    khi[kd] = (unsigned short)hb;
    klo[kd] = (unsigned short)f2bf(kv - bf2f(hb));
    hb = f2bf(vv);
    vthi[vd] = (unsigned short)hb;
    vtlo[vd] = (unsigned short)f2bf(vv - bf2f(hb));
}

// zero the 52 pad keys per head in all four split arrays
__global__ __launch_bounds__(256) void padzero_k(unsigned short* __restrict__ khi,
                                                 unsigned short* __restrict__ klo,
                                                 unsigned short* __restrict__ vthi,
                                                 unsigned short* __restrict__ vtlo) {
    int g = blockIdx.x * 256 + threadIdx.x;
    if (g >= NH * (NCATP - NCAT) * HD) return;
    int d = g & 63, rest = g >> 6;
    int i = rest % (NCATP - NCAT), h = rest / (NCATP - NCAT);
    size_t kd = ((size_t)h * NCATP + NCAT + i) * HD + d;
    size_t vd = ((size_t)h * HD + d) * NCATP + NCAT + i;
    khi[kd] = 0; klo[kd] = 0;
    vthi[vd] = 0; vtlo[vd] = 0;
}

// ---------------------------------------------------------------------------
// Final attention via bf16x3 MFMA.  Block = (head, 16 q rows), 4 waves.
// QK: wave w owns keys [w*192, w*192+192), scores in VGPRs (12 tiles x 4).
// Softmax: reg + shfl + LDS cross-wave.  P stored to LDS pre-split bf16.
// PV: wave w owns dims [w*16, w*16+16) over all 768 keys; A=P from LDS
// (ds_read_b128, no split VALU), B=V^T pre-split from global.
// ---------------------------------------------------------------------------
__global__ __launch_bounds__(256) void attn_mfma(const float* __restrict__ q,
                                                 const unsigned short* __restrict__ khi,
                                                 const unsigned short* __restrict__ klo,
                                                 const unsigned short* __restrict__ vthi,
                                                 const unsigned short* __restrict__ vtlo,
                                                 float* __restrict__ ao) {
    __shared__ unsigned short phi[16][776];   // 24.8 KB (pad 8: stride 1552B, 16B-aligned)
    __shared__ unsigned short plo[16][776];   // 24.8 KB
    __shared__ float redm[4][16], redl[4][16];
    int h  = blockIdx.x;
    int m0 = blockIdx.y * 16;
    int t  = threadIdx.x;
    int lane = t & 63, w = t >> 6;
    int quad = lane >> 4, c16 = lane & 15;

    // ---- A fragments (q rows) ----
    const float* qp = q + (size_t)(m0 + c16) * HID + h * HD;
    short8 Ah0, Al0, Ah1, Al1;
    {
        float4 a0 = *(const float4*)(qp + quad*8);
        float4 a1 = *(const float4*)(qp + quad*8 + 4);
        float4 a2 = *(const float4*)(qp + 32 + quad*8);
        float4 a3 = *(const float4*)(qp + 32 + quad*8 + 4);
        split8(a0, a1, Ah0, Al0);
        split8(a2, a3, Ah1, Al1);
    }

    // ---- QK^T: 12 tiles of 16 keys ----
    float sreg[12][4];
    #pragma unroll
    for (int nt = 0; nt < 12; ++nt) {
        int key = w*192 + nt*16 + c16;
        const unsigned short* kbh = khi + ((size_t)h * NCATP + key) * HD;
        const unsigned short* kbl = klo + ((size_t)h * NCATP + key) * HD;
        short8 Bh0 = *(const short8*)(kbh + quad*8);
        short8 Bh1 = *(const short8*)(kbh + 32 + quad*8);
        short8 Bl0 = *(const short8*)(kbl + quad*8);
        short8 Bl1 = *(const short8*)(kbl + 32 + quad*8);
        f32x4 acc = {0.f, 0.f, 0.f, 0.f};
        acc = __builtin_amdgcn_mfma_f32_16x16x32_bf16(Ah0, Bh0, acc, 0, 0, 0);
        acc = __builtin_amdgcn_mfma_f32_16x16x32_bf16(Al0, Bh0, acc, 0, 0, 0);
        acc = __builtin_amdgcn_mfma_f32_16x16x32_bf16(Ah0, Bl0, acc, 0, 0, 0);
        acc = __builtin_amdgcn_mfma_f32_16x16x32_bf16(Ah1, Bh1, acc, 0, 0, 0);
        acc = __builtin_amdgcn_mfma_f32_16x16x32_bf16(Al1, Bh1, acc, 0, 0, 0);
        acc = __builtin_amdgcn_mfma_f32_16x16x32_bf16(Ah1, Bl1, acc, 0, 0, 0);
        bool bad = key >= NCAT;
        #pragma unroll
        for (int i = 0; i < 4; ++i)
            sreg[nt][i] = bad ? -1e30f : acc[i] * SCALE;
    }

    // ---- softmax over 768 (masked) keys; rows quad*4+i ----
    float m[4], l[4];
    #pragma unroll
    for (int i = 0; i < 4; ++i) {
        float mm = -1e30f;
        #pragma unroll
        for (int nt = 0; nt < 12; ++nt) mm = fmaxf(mm, sreg[nt][i]);
        #pragma unroll
        for (int off = 1; off <= 8; off <<= 1) mm = fmaxf(mm, __shfl_xor(mm, off));
        m[i] = mm;
    }
    if (c16 == 0) {
        #pragma unroll
        for (int i = 0; i < 4; ++i) redm[w][quad*4 + i] = m[i];
    }
    __syncthreads();
    #pragma unroll
    for (int i = 0; i < 4; ++i) {
        int row = quad*4 + i;
        m[i] = fmaxf(fmaxf(redm[0][row], redm[1][row]),
                     fmaxf(redm[2][row], redm[3][row]));
    }
    #pragma unroll
    for (int i = 0; i < 4; ++i) {
        float ll = 0.f;
        #pragma unroll
        for (int nt = 0; nt < 12; ++nt) ll += expf(sreg[nt][i] - m[i]);
        #pragma unroll
        for (int off = 1; off <= 8; off <<= 1) ll += __shfl_xor(ll, off);
        l[i] = ll;
    }
    if (c16 == 0) {
        #pragma unroll
        for (int i = 0; i < 4; ++i) redl[w][quad*4 + i] = l[i];
    }
    __syncthreads();
    float inv[4];
    #pragma unroll
    for (int i = 0; i < 4; ++i) {
        int row = quad*4 + i;
        inv[i] = 1.f / (redl[0][row] + redl[1][row] + redl[2][row] + redl[3][row]);
    }

    // ---- probs -> LDS, pre-split bf16 ----
    #pragma unroll
    for (int nt = 0; nt < 12; ++nt) {
        int key = w*192 + nt*16 + c16;
        #pragma unroll
        for (int i = 0; i < 4; ++i) {
            float p = expf(sreg[nt][i] - m[i]) * inv[i];
            short ph = f2bf(p);
            phi[quad*4 + i][key] = (unsigned short)ph;
            plo[quad*4 + i][key] = (unsigned short)f2bf(p - bf2f(ph));
        }
    }
    __syncthreads();

    // ---- PV: wave w computes dims [w*16, w*16+16) over all 768 keys ----
    int dim = w*16 + c16;
    const unsigned short* vh = vthi + ((size_t)h * HD + dim) * NCATP;
    const unsigned short* vl = vtlo + ((size_t)h * HD + dim) * NCATP;
    f32x4 oacc = {0.f, 0.f, 0.f, 0.f};
    #pragma unroll 4
    for (int s = 0; s < 24; ++s) {
        int k0 = s*32 + quad*8;
        short8 Ph = *(const short8*)&phi[c16][k0];
        short8 Pl = *(const short8*)&plo[c16][k0];
        short8 Vh = *(const short8*)(vh + k0);
        short8 Vl = *(const short8*)(vl + k0);
        oacc = __builtin_amdgcn_mfma_f32_16x16x32_bf16(Ph, Vh, oacc, 0, 0, 0);
        oacc = __builtin_amdgcn_mfma_f32_16x16x32_bf16(Pl, Vh, oacc, 0, 0, 0);
        oacc = __builtin_amdgcn_mfma_f32_16x16x32_bf16(Ph, Vl, oacc, 0, 0, 0);
    }
    #pragma unroll
    for (int i = 0; i < 4; ++i)
        ao[(size_t)(m0 + quad*4 + i) * HID + h * HD + dim] = oacc[i];
}

// ---------------------------------------------------------------------------
extern "C" void kernel_launch(void* const* d_in, const int* in_sizes, int n_in,
                              void* d_out, int out_size, void* d_ws, size_t ws_size,
                              hipStream_t stream) {
    const float* x  = (const float*)d_in[0];
    const float* Wq = (const float*)d_in[1];
    const float* Wk = (const float*)d_in[2];
    const float* Wv = (const float*)d_in[3];
    const float* Wo = (const float*)d_in[4];
    float* out = (float*)d_out;

    float* ws   = (float*)d_ws;
    float* q    = ws;
    float* k    = q    + (size_t)SEQ*HID;
    float* v    = k    + (size_t)SEQ*HID;
    float* ao   = v    + (size_t)SEQ*HID;
    float* ent  = ao   + (size_t)SEQ*HID;
    float* mxa  = ent  + NH*SEQ;
    float* infl = mxa  + NH*SEQ;
    float* imp  = infl + SEQ;
    int*   hh   = (int*)(imp + SEQ);
    float* wk   = (float*)(hh + 256);
    float* wv   = wk   + NH*SEQ;
    unsigned short* khi  = (unsigned short*)(wv + NH*SEQ);   // [h][768][64]
    unsigned short* klo  = khi  + (size_t)NH*NCATP*HD;
    unsigned short* vthi = klo  + (size_t)NH*NCATP*HD;       // [h][64][768]
    unsigned short* vtlo = vthi + (size_t)NH*NCATP*HD;

    dim3 gB(16, 32);
    gemm_f32<<<gB, 256, 0, stream>>>(x, Wq, q, SEQ, HID, HID);
    gemm_f32<<<gB, 256, 0, stream>>>(x, Wk, k, SEQ, HID, HID);
    gemm_f32<<<gB, 256, 0, stream>>>(x, Wv, v, SEQ, HID, HID);

    hipMemsetAsync(infl, 0, SEQ * sizeof(float), stream);
    score_mfma<<<dim3(NH, SEQ/16), 256, 0, stream>>>(q, k, ent, mxa, infl);
    importance_k<<<SEQ/256, 256, 0, stream>>>(ent, mxa, infl, imp);
    topk_k<<<SEQ/256, 256, 0, stream>>>(imp, hh);

    norms_k<<<NH*SEQ/4, 256, 0, stream>>>(k, wk);
    norms_k<<<NH*SEQ/4, 256, 0, stream>>>(v, wv);
    softw_k<<<NH, 256, 0, stream>>>(wk);
    softw_k<<<NH, 256, 0, stream>>>(wv);
    poolk_k<<<NH*LCOMP*HD/256, 256, 0, stream>>>(k, wk, khi, klo);
    poolv_k<<<NH*LCOMP*HD/256, 256, 0, stream>>>(v, wv, vthi, vtlo);
    padzero_k<<<208, 256, 0, stream>>>(khi, klo, vthi, vtlo);
    gather_k<<<NH*NKH*HD/256, 256, 0, stream>>>(k, v, hh, khi, klo, vthi, vtlo);

    attn_mfma<<<dim3(NH, SEQ/16), 256, 0, stream>>>(q, khi, klo, vthi, vtlo, ao);
    gemm_f32<<<gB, 256, 0, stream>>>(ao, Wo, out, SEQ, HID, HID);
}

// Round 5
// 675.079 us; speedup vs baseline: 9.2921x; 1.1520x over previous
//
#include <hip/hip_runtime.h>
#include <math.h>

#define SEQ   2048
#define HID   1024
#define NH    16
#define HD    64
#define NKH   204          // heavy hitters = int(2048*0.1)
#define LCOMP 512          // compressed length = 2048/4
#define NCAT  716          // 204 + 512
#define NCATP 768          // padded to multiple of 64 (52 pad keys)
#define SCALE 0.125f       // 1/sqrt(64)

typedef __attribute__((ext_vector_type(8))) short short8;   // 8 bf16 (4 VGPRs)
typedef __attribute__((ext_vector_type(4))) float f32x4;    // MFMA accumulator

// ---- bf16 split helpers (RNE) -------------------------------------------
__device__ __forceinline__ short f2bf(float f) {
    unsigned u = __builtin_bit_cast(unsigned, f);
    u += 0x7FFFu + ((u >> 16) & 1u);
    return (short)(u >> 16);
}
__device__ __forceinline__ float bf2f(short h) {
    unsigned u = ((unsigned)(unsigned short)h) << 16;
    return __builtin_bit_cast(float, u);
}

// ---------------------------------------------------------------------------
// One-pass splitters: f32 -> bf16 hi/lo.  splitx keeps layout; splitw
// transposes [k][n] -> [n][k] via LDS tile so both sides stay coalesced.
// ---------------------------------------------------------------------------
__global__ __launch_bounds__(256) void splitx_k(const float* __restrict__ X,
                                                unsigned short* __restrict__ hi,
                                                unsigned short* __restrict__ lo) {
    size_t g = ((size_t)blockIdx.x * 256 + threadIdx.x) * 4;
    float4 v4 = *(const float4*)(X + g);
    ushort4 h4, l4;
    short hb;
    hb = f2bf(v4.x); h4.x = hb; l4.x = (unsigned short)f2bf(v4.x - bf2f(hb));
    hb = f2bf(v4.y); h4.y = hb; l4.y = (unsigned short)f2bf(v4.y - bf2f(hb));
    hb = f2bf(v4.z); h4.z = hb; l4.z = (unsigned short)f2bf(v4.z - bf2f(hb));
    hb = f2bf(v4.w); h4.w = hb; l4.w = (unsigned short)f2bf(v4.w - bf2f(hb));
    *(ushort4*)(hi + g) = h4;
    *(ushort4*)(lo + g) = l4;
}

__global__ __launch_bounds__(256) void splitw_k(const float* __restrict__ W,
                                                unsigned short* __restrict__ hi,
                                                unsigned short* __restrict__ lo) {
    __shared__ float tile[64][65];
    int n0 = blockIdx.x * 64, k0 = blockIdx.y * 64;
    int t = threadIdx.x;
    int r = t >> 4, c4 = (t & 15) * 4;
    #pragma unroll
    for (int i = 0; i < 4; ++i) {
        float4 v4 = *(const float4*)(W + (size_t)(k0 + i*16 + r) * HID + n0 + c4);
        tile[i*16 + r][c4+0] = v4.x; tile[i*16 + r][c4+1] = v4.y;
        tile[i*16 + r][c4+2] = v4.z; tile[i*16 + r][c4+3] = v4.w;
    }
    __syncthreads();
    #pragma unroll
    for (int i = 0; i < 4; ++i) {
        int n = i*16 + r;
        float v0 = tile[c4+0][n], v1 = tile[c4+1][n];
        float v2 = tile[c4+2][n], v3 = tile[c4+3][n];
        ushort4 h4, l4;
        short hb;
        hb = f2bf(v0); h4.x = hb; l4.x = (unsigned short)f2bf(v0 - bf2f(hb));
        hb = f2bf(v1); h4.y = hb; l4.y = (unsigned short)f2bf(v1 - bf2f(hb));
        hb = f2bf(v2); h4.z = hb; l4.z = (unsigned short)f2bf(v2 - bf2f(hb));
        hb = f2bf(v3); h4.w = hb; l4.w = (unsigned short)f2bf(v3 - bf2f(hb));
        size_t o = (size_t)(n0 + n) * HID + k0 + c4;
        *(ushort4*)(hi + o) = h4;
        *(ushort4*)(lo + o) = l4;
    }
}

// ---------------------------------------------------------------------------
// bf16x3 MFMA GEMM: C[2048,1024] = A[2048,1024] @ B[1024,1024].
// A pre-split [m][k]; B pre-split TRANSPOSED [n][k].  Grid (64,8), 4 waves;
// wave = 32m x 32n.  Optional f32 C and optional per-head-split bf16 out.
// ---------------------------------------------------------------------------
__global__ __launch_bounds__(256) void gemm_sp(const unsigned short* __restrict__ Ahi,
                                               const unsigned short* __restrict__ Alo,
                                               const unsigned short* __restrict__ Bthi,
                                               const unsigned short* __restrict__ Btlo,
                                               float* __restrict__ Cf,
                                               unsigned short* __restrict__ Hhi,
                                               unsigned short* __restrict__ Hlo) {
    int t = threadIdx.x, lane = t & 63, w = t >> 6;
    int quad = lane >> 4, c16 = lane & 15;
    int m0 = blockIdx.x * 32;
    int nw = blockIdx.y * 128 + w * 32;
    const unsigned short* a0h = Ahi + (size_t)(m0 + c16) * HID;
    const unsigned short* a0l = Alo + (size_t)(m0 + c16) * HID;
    const unsigned short* b0h = Bthi + (size_t)(nw + c16) * HID;
    const unsigned short* b0l = Btlo + (size_t)(nw + c16) * HID;
    f32x4 acc[2][2];
    #pragma unroll
    for (int mt = 0; mt < 2; ++mt)
        #pragma unroll
        for (int nt = 0; nt < 2; ++nt)
            acc[mt][nt] = (f32x4){0.f, 0.f, 0.f, 0.f};
    #pragma unroll 2
    for (int kc = 0; kc < 32; ++kc) {
        int ko = kc * 32 + quad * 8;
        short8 Ah0 = *(const short8*)(a0h + ko);
        short8 Al0 = *(const short8*)(a0l + ko);
        short8 Ah1 = *(const short8*)(a0h + 16 * HID + ko);
        short8 Al1 = *(const short8*)(a0l + 16 * HID + ko);
        #pragma unroll
        for (int nt = 0; nt < 2; ++nt) {
            short8 Bh = *(const short8*)(b0h + nt * 16 * HID + ko);
            short8 Bl = *(const short8*)(b0l + nt * 16 * HID + ko);
            acc[0][nt] = __builtin_amdgcn_mfma_f32_16x16x32_bf16(Ah0, Bh, acc[0][nt], 0, 0, 0);
            acc[0][nt] = __builtin_amdgcn_mfma_f32_16x16x32_bf16(Al0, Bh, acc[0][nt], 0, 0, 0);
            acc[0][nt] = __builtin_amdgcn_mfma_f32_16x16x32_bf16(Ah0, Bl, acc[0][nt], 0, 0, 0);
            acc[1][nt] = __builtin_amdgcn_mfma_f32_16x16x32_bf16(Ah1, Bh, acc[1][nt], 0, 0, 0);
            acc[1][nt] = __builtin_amdgcn_mfma_f32_16x16x32_bf16(Al1, Bh, acc[1][nt], 0, 0, 0);
            acc[1][nt] = __builtin_amdgcn_mfma_f32_16x16x32_bf16(Ah1, Bl, acc[1][nt], 0, 0, 0);
        }
    }
    #pragma unroll
    for (int mt = 0; mt < 2; ++mt)
    #pragma unroll
    for (int nt = 0; nt < 2; ++nt)
    #pragma unroll
    for (int i = 0; i < 4; ++i) {
        int m = m0 + mt*16 + quad*4 + i;
        int n = nw + nt*16 + c16;
        float val = acc[mt][nt][i];
        if (Cf) Cf[(size_t)m * HID + n] = val;
        if (Hhi) {
            int hh_ = n >> 6, d = n & 63;
            size_t o = ((size_t)hh_ * SEQ + m) * HD + d;
            short hb = f2bf(val);
            Hhi[o] = (unsigned short)hb;
            Hlo[o] = (unsigned short)f2bf(val - bf2f(hb));
        }
    }
}

// ---------------------------------------------------------------------------
// Score stats via bf16x3 MFMA, v2: pre-split q/k fragments (zero split VALU),
// single expf pass (exp overwrites sreg), analytic entropy (no per-score log).
// Block = (head, 16 q rows), wave w owns keys [w*512, +512).
// ---------------------------------------------------------------------------
__global__ __launch_bounds__(256) void score_mfma(const unsigned short* __restrict__ qhi,
                                                  const unsigned short* __restrict__ qlo,
                                                  const unsigned short* __restrict__ khi,
                                                  const unsigned short* __restrict__ klo,
                                                  float* __restrict__ ent,
                                                  float* __restrict__ mxa,
                                                  float* __restrict__ infl) {
    __shared__ float redm[4][16], redl[4][16], rede[4][16];
    int h  = blockIdx.x;
    int m0 = blockIdx.y * 16;
    int t  = threadIdx.x;
    int lane = t & 63, w = t >> 6;
    int quad = lane >> 4, c16 = lane & 15;

    const unsigned short* qph = qhi + ((size_t)h * SEQ + m0 + c16) * HD;
    const unsigned short* qpl = qlo + ((size_t)h * SEQ + m0 + c16) * HD;
    short8 Ah0 = *(const short8*)(qph + quad*8);
    short8 Ah1 = *(const short8*)(qph + 32 + quad*8);
    short8 Al0 = *(const short8*)(qpl + quad*8);
    short8 Al1 = *(const short8*)(qpl + 32 + quad*8);

    float sreg[32][4];
    #pragma unroll
    for (int nt = 0; nt < 32; ++nt) {
        int key = (w * 32 + nt) * 16 + c16;
        const unsigned short* kbh = khi + ((size_t)h * SEQ + key) * HD;
        const unsigned short* kbl = klo + ((size_t)h * SEQ + key) * HD;
        short8 Bh0 = *(const short8*)(kbh + quad*8);
        short8 Bh1 = *(const short8*)(kbh + 32 + quad*8);
        short8 Bl0 = *(const short8*)(kbl + quad*8);
        short8 Bl1 = *(const short8*)(kbl + 32 + quad*8);
        f32x4 acc = {0.f, 0.f, 0.f, 0.f};
        acc = __builtin_amdgcn_mfma_f32_16x16x32_bf16(Ah0, Bh0, acc, 0, 0, 0);
        acc = __builtin_amdgcn_mfma_f32_16x16x32_bf16(Al0, Bh0, acc, 0, 0, 0);
        acc = __builtin_amdgcn_mfma_f32_16x16x32_bf16(Ah0, Bl0, acc, 0, 0, 0);
        acc = __builtin_amdgcn_mfma_f32_16x16x32_bf16(Ah1, Bh1, acc, 0, 0, 0);
        acc = __builtin_amdgcn_mfma_f32_16x16x32_bf16(Al1, Bh1, acc, 0, 0, 0);
        acc = __builtin_amdgcn_mfma_f32_16x16x32_bf16(Ah1, Bl1, acc, 0, 0, 0);
        #pragma unroll
        for (int i = 0; i < 4; ++i) sreg[nt][i] = acc[i] * SCALE;
    }

    // ---- global row max ----
    float m[4];
    #pragma unroll
    for (int i = 0; i < 4; ++i) {
        float mm = -1e30f;
        #pragma unroll
        for (int nt = 0; nt < 32; ++nt) mm = fmaxf(mm, sreg[nt][i]);
        #pragma unroll
        for (int off = 1; off <= 8; off <<= 1) mm = fmaxf(mm, __shfl_xor(mm, off));
        m[i] = mm;
    }
    if (c16 == 0) {
        #pragma unroll
        for (int i = 0; i < 4; ++i) redm[w][quad*4 + i] = m[i];
    }
    __syncthreads();
    #pragma unroll
    for (int i = 0; i < 4; ++i) {
        int row = quad*4 + i;
        m[i] = fmaxf(fmaxf(redm[0][row], redm[1][row]),
                     fmaxf(redm[2][row], redm[3][row]));
    }

    // ---- single exp pass: l = sum(t), ee = sum(t*d); sreg <- t ----
    float l[4], ee[4];
    #pragma unroll
    for (int i = 0; i < 4; ++i) {
        float ll = 0.f, e2 = 0.f;
        #pragma unroll
        for (int nt = 0; nt < 32; ++nt) {
            float d = sreg[nt][i] - m[i];
            float tt = expf(d);
            sreg[nt][i] = tt;
            ll += tt;
            e2 += tt * d;
        }
        #pragma unroll
        for (int off = 1; off <= 8; off <<= 1) {
            ll += __shfl_xor(ll, off);
            e2 += __shfl_xor(e2, off);
        }
        l[i] = ll; ee[i] = e2;
    }
    if (c16 == 0) {
        #pragma unroll
        for (int i = 0; i < 4; ++i) { redl[w][quad*4 + i] = l[i]; rede[w][quad*4 + i] = ee[i]; }
    }
    __syncthreads();
    float inv[4];
    #pragma unroll
    for (int i = 0; i < 4; ++i) {
        int row = quad*4 + i;
        l[i]  = redl[0][row] + redl[1][row] + redl[2][row] + redl[3][row];
        ee[i] = rede[0][row] + rede[1][row] + rede[2][row] + rede[3][row];
        inv[i] = 1.f / l[i];
    }
    if (w == 0 && c16 == 0) {
        #pragma unroll
        for (int i = 0; i < 4; ++i) {
            mxa[h*SEQ + m0 + quad*4 + i] = inv[i];
            // entropy = -sum p ln p = ln(l) - (sum t*d)/l   (clip at p<1e-8 negligible)
            ent[h*SEQ + m0 + quad*4 + i] = logf(l[i]) - ee[i] * inv[i];
        }
    }

    // ---- influence: column sums of p over this block's 16 rows ----
    #pragma unroll
    for (int nt = 0; nt < 32; ++nt) {
        float cs = sreg[nt][0]*inv[0] + sreg[nt][1]*inv[1]
                 + sreg[nt][2]*inv[2] + sreg[nt][3]*inv[3];
        cs += __shfl_xor(cs, 16);
        cs += __shfl_xor(cs, 32);
        if (lane < 16) atomicAdd(&infl[(w*32 + nt)*16 + lane], cs);
    }
}

__global__ __launch_bounds__(256) void importance_k(const float* __restrict__ ent,
                                                    const float* __restrict__ mxa,
                                                    const float* __restrict__ infl,
                                                    float* __restrict__ imp) {
    int s = blockIdx.x * 256 + threadIdx.x;
    float es = 0.f, ms = 0.f;
    #pragma unroll
    for (int h = 0; h < NH; ++h) { es += ent[h*SEQ + s]; ms += mxa[h*SEQ + s]; }
    imp[s] = (-0.4f*es + 0.3f*ms + 0.3f*infl[s]) * (1.f/16.f);
}

// Deterministic top-k by rank counting (matches lax.top_k set semantics).
__global__ __launch_bounds__(256) void topk_k(const float* __restrict__ imp,
                                              int* __restrict__ hh) {
    __shared__ float si[SEQ];
    int t = threadIdx.x, s = blockIdx.x * 256 + t;
    for (int i = t; i < SEQ; i += 256) si[i] = imp[i];
    __syncthreads();
    float v = si[s];
    int rank = 0;
    #pragma unroll 1
    for (int i = 0; i < SEQ; ++i) {
        float u = si[i];
        rank += (u > v) || (u == v && i < s);
    }
    if (rank < NKH) hh[rank] = s;
}

// per-(h,s) L2 norm of a 64-dim head vector (one wave each)
__global__ __launch_bounds__(256) void norms_k(const float* __restrict__ x,
                                               float* __restrict__ n) {
    int t = threadIdx.x;
    int wid = blockIdx.x * 4 + (t >> 6);
    int lane = t & 63;
    int h = wid >> 11, s = wid & 2047;
    float v = x[(size_t)s * HID + h * HD + lane];
    float ss = v * v;
    #pragma unroll
    for (int off = 32; off; off >>= 1) ss += __shfl_xor(ss, off);
    if (lane == 0) n[h*SEQ + s] = sqrtf(ss);
}

// in-place softmax over SEQ per head (one block per head)
__global__ __launch_bounds__(256) void softw_k(float* __restrict__ n) {
    __shared__ float red[8];
    int h = blockIdx.x, t = threadIdx.x, lane = t & 63, w = t >> 6;
    float* nh = n + (size_t)h * SEQ;
    float m = -1e30f;
    for (int i = t; i < SEQ; i += 256) m = fmaxf(m, nh[i]);
    #pragma unroll
    for (int off = 32; off; off >>= 1) m = fmaxf(m, __shfl_xor(m, off));
    if (lane == 0) red[w] = m;
    __syncthreads();
    m = fmaxf(fmaxf(red[0], red[1]), fmaxf(red[2], red[3]));
    float z = 0.f;
    for (int i = t; i < SEQ; i += 256) z += expf(nh[i] - m);
    #pragma unroll
    for (int off = 32; off; off >>= 1) z += __shfl_xor(z, off);
    if (lane == 0) red[4 + w] = z;
    __syncthreads();
    z = red[4] + red[5] + red[6] + red[7];
    for (int i = t; i < SEQ; i += 256) nh[i] = expf(nh[i] - m) / z;
}

// group-4 weighted pooling of K -> pre-split bf16 [h][key][d]
__global__ __launch_bounds__(256) void poolk_k(const float* __restrict__ src,
                                               const float* __restrict__ w,
                                               unsigned short* __restrict__ hi,
                                               unsigned short* __restrict__ lo) {
    int g = blockIdx.x * 256 + threadIdx.x;
    int d = g & 63, rest = g >> 6;
    int l = rest & 511, h = rest >> 9;
    const float* wp = w + (size_t)h * SEQ + l * 4;
    float w0 = wp[0], w1 = wp[1], w2 = wp[2], w3 = wp[3];
    float wsum = w0 + w1 + w2 + w3 + 1e-8f;
    size_t base = (size_t)(l*4) * HID + h * HD + d;
    float val = (src[base]*w0 + src[base+HID]*w1 + src[base+2*HID]*w2 + src[base+3*HID]*w3) / wsum;
    size_t dst = ((size_t)h * NCATP + NKH + l) * HD + d;
    short hb = f2bf(val);
    hi[dst] = (unsigned short)hb;
    lo[dst] = (unsigned short)f2bf(val - bf2f(hb));
}

// group-4 weighted pooling of V -> pre-split bf16 TRANSPOSED [h][d][key]
__global__ __launch_bounds__(256) void poolv_k(const float* __restrict__ src,
                                               const float* __restrict__ w,
                                               unsigned short* __restrict__ hi,
                                               unsigned short* __restrict__ lo) {
    int g = blockIdx.x * 256 + threadIdx.x;
    int d = g & 63, rest = g >> 6;
    int l = rest & 511, h = rest >> 9;
    const float* wp = w + (size_t)h * SEQ + l * 4;
    float w0 = wp[0], w1 = wp[1], w2 = wp[2], w3 = wp[3];
    float wsum = w0 + w1 + w2 + w3 + 1e-8f;
    size_t base = (size_t)(l*4) * HID + h * HD + d;
    float val = (src[base]*w0 + src[base+HID]*w1 + src[base+2*HID]*w2 + src[base+3*HID]*w3) / wsum;
    size_t dst = ((size_t)h * HD + d) * NCATP + NKH + l;
    short hb = f2bf(val);
    hi[dst] = (unsigned short)hb;
    lo[dst] = (unsigned short)f2bf(val - bf2f(hb));
}

// gather heavy-hitter k/v rows -> pre-split bf16 (K direct, V transposed)
__global__ __launch_bounds__(256) void gather_k(const float* __restrict__ k,
                                                const float* __restrict__ v,
                                                const int* __restrict__ hh,
                                                unsigned short* __restrict__ khi,
                                                unsigned short* __restrict__ klo,
                                                unsigned short* __restrict__ vthi,
                                                unsigned short* __restrict__ vtlo) {
    int g = blockIdx.x * 256 + threadIdx.x;
    int d = g & 63, rest = g >> 6;
    int i = rest % NKH, h = rest / NKH;
    int s = hh[i];
    float kv = k[(size_t)s * HID + h * HD + d];
    float vv = v[(size_t)s * HID + h * HD + d];
    size_t kd = ((size_t)h * NCATP + i) * HD + d;
    size_t vd = ((size_t)h * HD + d) * NCATP + i;
    short hb = f2bf(kv);
    khi[kd] = (unsigned short)hb;
    klo[kd] = (unsigned short)f2bf(kv - bf2f(hb));
    hb = f2bf(vv);
    vthi[vd] = (unsigned short)hb;
    vtlo[vd] = (unsigned short)f2bf(vv - bf2f(hb));
}

// zero the 52 pad keys per head in all four split arrays
__global__ __launch_bounds__(256) void padzero_k(unsigned short* __restrict__ khi,
                                                 unsigned short* __restrict__ klo,
                                                 unsigned short* __restrict__ vthi,
                                                 unsigned short* __restrict__ vtlo) {
    int g = blockIdx.x * 256 + threadIdx.x;
    if (g >= NH * (NCATP - NCAT) * HD) return;
    int d = g & 63, rest = g >> 6;
    int i = rest % (NCATP - NCAT), h = rest / (NCATP - NCAT);
    size_t kd = ((size_t)h * NCATP + NCAT + i) * HD + d;
    size_t vd = ((size_t)h * HD + d) * NCATP + NCAT + i;
    khi[kd] = 0; klo[kd] = 0;
    vthi[vd] = 0; vtlo[vd] = 0;
}

// ---------------------------------------------------------------------------
// Final attention via bf16x3 MFMA.  Q from pre-split qsp; output emitted as
// pre-split bf16 [m][k] for the final GEMM (no f32 round-trip).
// ---------------------------------------------------------------------------
__global__ __launch_bounds__(256) void attn_mfma(const unsigned short* __restrict__ qhi,
                                                 const unsigned short* __restrict__ qlo,
                                                 const unsigned short* __restrict__ kchi,
                                                 const unsigned short* __restrict__ kclo,
                                                 const unsigned short* __restrict__ vthi,
                                                 const unsigned short* __restrict__ vtlo,
                                                 unsigned short* __restrict__ aohi,
                                                 unsigned short* __restrict__ aolo) {
    __shared__ unsigned short phi[16][776];   // 24.8 KB
    __shared__ unsigned short plo[16][776];   // 24.8 KB
    __shared__ float redm[4][16], redl[4][16];
    int h  = blockIdx.x;
    int m0 = blockIdx.y * 16;
    int t  = threadIdx.x;
    int lane = t & 63, w = t >> 6;
    int quad = lane >> 4, c16 = lane & 15;

    const unsigned short* qph = qhi + ((size_t)h * SEQ + m0 + c16) * HD;
    const unsigned short* qpl = qlo + ((size_t)h * SEQ + m0 + c16) * HD;
    short8 Ah0 = *(const short8*)(qph + quad*8);
    short8 Ah1 = *(const short8*)(qph + 32 + quad*8);
    short8 Al0 = *(const short8*)(qpl + quad*8);
    short8 Al1 = *(const short8*)(qpl + 32 + quad*8);

    // ---- QK^T: 12 tiles of 16 keys ----
    float sreg[12][4];
    #pragma unroll
    for (int nt = 0; nt < 12; ++nt) {
        int key = w*192 + nt*16 + c16;
        const unsigned short* kbh = kchi + ((size_t)h * NCATP + key) * HD;
        const unsigned short* kbl = kclo + ((size_t)h * NCATP + key) * HD;
        short8 Bh0 = *(const short8*)(kbh + quad*8);
        short8 Bh1 = *(const short8*)(kbh + 32 + quad*8);
        short8 Bl0 = *(const short8*)(kbl + quad*8);
        short8 Bl1 = *(const short8*)(kbl + 32 + quad*8);
        f32x4 acc = {0.f, 0.f, 0.f, 0.f};
        acc = __builtin_amdgcn_mfma_f32_16x16x32_bf16(Ah0, Bh0, acc, 0, 0, 0);
        acc = __builtin_amdgcn_mfma_f32_16x16x32_bf16(Al0, Bh0, acc, 0, 0, 0);
        acc = __builtin_amdgcn_mfma_f32_16x16x32_bf16(Ah0, Bl0, acc, 0, 0, 0);
        acc = __builtin_amdgcn_mfma_f32_16x16x32_bf16(Ah1, Bh1, acc, 0, 0, 0);
        acc = __builtin_amdgcn_mfma_f32_16x16x32_bf16(Al1, Bh1, acc, 0, 0, 0);
        acc = __builtin_amdgcn_mfma_f32_16x16x32_bf16(Ah1, Bl1, acc, 0, 0, 0);
        bool bad = key >= NCAT;
        #pragma unroll
        for (int i = 0; i < 4; ++i)
            sreg[nt][i] = bad ? -1e30f : acc[i] * SCALE;
    }

    // ---- softmax ----
    float m[4], l[4];
    #pragma unroll
    for (int i = 0; i < 4; ++i) {
        float mm = -1e30f;
        #pragma unroll
        for (int nt = 0; nt < 12; ++nt) mm = fmaxf(mm, sreg[nt][i]);
        #pragma unroll
        for (int off = 1; off <= 8; off <<= 1) mm = fmaxf(mm, __shfl_xor(mm, off));
        m[i] = mm;
    }
    if (c16 == 0) {
        #pragma unroll
        for (int i = 0; i < 4; ++i) redm[w][quad*4 + i] = m[i];
    }
    __syncthreads();
    #pragma unroll
    for (int i = 0; i < 4; ++i) {
        int row = quad*4 + i;
        m[i] = fmaxf(fmaxf(redm[0][row], redm[1][row]),
                     fmaxf(redm[2][row], redm[3][row]));
    }
    #pragma unroll
    for (int i = 0; i < 4; ++i) {
        float ll = 0.f;
        #pragma unroll
        for (int nt = 0; nt < 12; ++nt) ll += expf(sreg[nt][i] - m[i]);
        #pragma unroll
        for (int off = 1; off <= 8; off <<= 1) ll += __shfl_xor(ll, off);
        l[i] = ll;
    }
    if (c16 == 0) {
        #pragma unroll
        for (int i = 0; i < 4; ++i) redl[w][quad*4 + i] = l[i];
    }
    __syncthreads();
    float inv[4];
    #pragma unroll
    for (int i = 0; i < 4; ++i) {
        int row = quad*4 + i;
        inv[i] = 1.f / (redl[0][row] + redl[1][row] + redl[2][row] + redl[3][row]);
    }

    // ---- probs -> LDS, pre-split bf16 ----
    #pragma unroll
    for (int nt = 0; nt < 12; ++nt) {
        int key = w*192 + nt*16 + c16;
        #pragma unroll
        for (int i = 0; i < 4; ++i) {
            float p = expf(sreg[nt][i] - m[i]) * inv[i];
            short ph = f2bf(p);
            phi[quad*4 + i][key] = (unsigned short)ph;
            plo[quad*4 + i][key] = (unsigned short)f2bf(p - bf2f(ph));
        }
    }
    __syncthreads();

    // ---- PV: wave w computes dims [w*16, w*16+16) over all 768 keys ----
    int dim = w*16 + c16;
    const unsigned short* vh = vthi + ((size_t)h * HD + dim) * NCATP;
    const unsigned short* vl = vtlo + ((size_t)h * HD + dim) * NCATP;
    f32x4 oacc = {0.f, 0.f, 0.f, 0.f};
    #pragma unroll 4
    for (int s = 0; s < 24; ++s) {
        int k0 = s*32 + quad*8;
        short8 Ph = *(const short8*)&phi[c16][k0];
        short8 Pl = *(const short8*)&plo[c16][k0];
        short8 Vh = *(const short8*)(vh + k0);
        short8 Vl = *(const short8*)(vl + k0);
        oacc = __builtin_amdgcn_mfma_f32_16x16x32_bf16(Ph, Vh, oacc, 0, 0, 0);
        oacc = __builtin_amdgcn_mfma_f32_16x16x32_bf16(Pl, Vh, oacc, 0, 0, 0);
        oacc = __builtin_amdgcn_mfma_f32_16x16x32_bf16(Ph, Vl, oacc, 0, 0, 0);
    }
    #pragma unroll
    for (int i = 0; i < 4; ++i) {
        float val = oacc[i];
        size_t o = (size_t)(m0 + quad*4 + i) * HID + h * HD + dim;
        short hb = f2bf(val);
        aohi[o] = (unsigned short)hb;
        aolo[o] = (unsigned short)f2bf(val - bf2f(hb));
    }
}

// ---------------------------------------------------------------------------
extern "C" void kernel_launch(void* const* d_in, const int* in_sizes, int n_in,
                              void* d_out, int out_size, void* d_ws, size_t ws_size,
                              hipStream_t stream) {
    const float* x  = (const float*)d_in[0];
    const float* Wq = (const float*)d_in[1];
    const float* Wk = (const float*)d_in[2];
    const float* Wv = (const float*)d_in[3];
    const float* Wo = (const float*)d_in[4];
    float* out = (float*)d_out;

    char* base = (char*)d_ws;                       // ~52.6 MB total
    const size_t MB = 1u << 20;
    float* kf = (float*)(base + 0);                 // 8 MB
    float* vf = (float*)(base + 8*MB);              // 8 MB
    unsigned short* xhi = (unsigned short*)(base + 16*MB);   // 4 MB
    unsigned short* xlo = (unsigned short*)(base + 20*MB);   // 4 MB
    unsigned short* w1hi = (unsigned short*)(base + 24*MB);  // 2 MB (Wq, later Wo)
    unsigned short* w1lo = (unsigned short*)(base + 26*MB);
    unsigned short* w2hi = (unsigned short*)(base + 28*MB);  // Wk
    unsigned short* w2lo = (unsigned short*)(base + 30*MB);
    unsigned short* w3hi = (unsigned short*)(base + 32*MB);  // Wv
    unsigned short* w3lo = (unsigned short*)(base + 34*MB);
    unsigned short* qsphi = (unsigned short*)(base + 36*MB); // 4 MB [h][s][d]
    unsigned short* qsplo = (unsigned short*)(base + 40*MB);
    unsigned short* ksphi = (unsigned short*)(base + 44*MB); // 4 MB [h][s][d]
    unsigned short* ksplo = (unsigned short*)(base + 48*MB);
    // aliases (ordered reuse, safe on an in-order stream):
    unsigned short* aohi = xhi;                     // after QKV gemms read xsp
    unsigned short* aolo = xlo;
    const size_t CATB = (size_t)NH * NCATP * HD * 2; // 1.5 MB
    unsigned short* kchi = (unsigned short*)(base + 44*MB);          // after score_mfma
    unsigned short* kclo = (unsigned short*)(base + 44*MB + CATB);
    unsigned short* vthi = (unsigned short*)(base + 44*MB + 2*CATB);
    unsigned short* vtlo = (unsigned short*)(base + 44*MB + 3*CATB);
    // small buffers
    char* sm = base + 52*MB;
    float* ent  = (float*)sm;                 sm += NH*SEQ*4;
    float* mxa  = (float*)sm;                 sm += NH*SEQ*4;
    float* infl = (float*)sm;                 sm += SEQ*4;
    float* imp  = (float*)sm;                 sm += SEQ*4;
    int*   hh   = (int*)sm;                   sm += 256*4;
    float* wk   = (float*)sm;                 sm += NH*SEQ*4;
    float* wv   = (float*)sm;

    // 1. split inputs
    splitx_k<<<SEQ*HID/1024, 256, 0, stream>>>(x, xhi, xlo);
    splitw_k<<<dim3(16,16), 256, 0, stream>>>(Wq, w1hi, w1lo);
    splitw_k<<<dim3(16,16), 256, 0, stream>>>(Wk, w2hi, w2lo);
    splitw_k<<<dim3(16,16), 256, 0, stream>>>(Wv, w3hi, w3lo);

    // 2. projections (bf16x3 MFMA)
    dim3 gG(64, 8);
    gemm_sp<<<gG, 256, 0, stream>>>(xhi, xlo, w1hi, w1lo, nullptr, qsphi, qsplo);
    gemm_sp<<<gG, 256, 0, stream>>>(xhi, xlo, w2hi, w2lo, kf, ksphi, ksplo);
    gemm_sp<<<gG, 256, 0, stream>>>(xhi, xlo, w3hi, w3lo, vf, nullptr, nullptr);

    // 3. Wo split (reuses Wq slot; gemm_q already consumed it)
    splitw_k<<<dim3(16,16), 256, 0, stream>>>(Wo, w1hi, w1lo);

    // 4. score stats + heavy hitters
    hipMemsetAsync(infl, 0, SEQ * sizeof(float), stream);
    score_mfma<<<dim3(NH, SEQ/16), 256, 0, stream>>>(qsphi, qsplo, ksphi, ksplo, ent, mxa, infl);
    importance_k<<<SEQ/256, 256, 0, stream>>>(ent, mxa, infl, imp);
    topk_k<<<SEQ/256, 256, 0, stream>>>(imp, hh);

    // 5. compression weights + cat building (cat arrays reuse ksp slot)
    norms_k<<<NH*SEQ/4, 256, 0, stream>>>(kf, wk);
    norms_k<<<NH*SEQ/4, 256, 0, stream>>>(vf, wv);
    softw_k<<<NH, 256, 0, stream>>>(wk);
    softw_k<<<NH, 256, 0, stream>>>(wv);
    poolk_k<<<NH*LCOMP*HD/256, 256, 0, stream>>>(kf, wk, kchi, kclo);
    poolv_k<<<NH*LCOMP*HD/256, 256, 0, stream>>>(vf, wv, vthi, vtlo);
    padzero_k<<<208, 256, 0, stream>>>(kchi, kclo, vthi, vtlo);
    gather_k<<<NH*NKH*HD/256, 256, 0, stream>>>(kf, vf, hh, kchi, kclo, vthi, vtlo);

    // 6. final attention (writes pre-split ao into xsp slot)
    attn_mfma<<<dim3(NH, SEQ/16), 256, 0, stream>>>(qsphi, qsplo, kchi, kclo, vthi, vtlo, aohi, aolo);

    // 7. output projection
    gemm_sp<<<gG, 256, 0, stream>>>(aohi, aolo, w1hi, w1lo, out, nullptr, nullptr);
}